// Round 9
// baseline (394.152 us; speedup 1.0000x reference)
//
#include <hip/hip_runtime.h>

typedef __bf16 bf16x8 __attribute__((ext_vector_type(8)));
typedef float f32x4 __attribute__((ext_vector_type(4)));

__device__ __forceinline__ unsigned short f2bf(float f) {
    unsigned int u = __float_as_uint(f);
    unsigned int r = (u + 0x7FFFu + ((u >> 16) & 1u)) >> 16;
    return (unsigned short)r;
}

__device__ __forceinline__ void gload16(const void* g, void* l) {
    __builtin_amdgcn_global_load_lds(
        (const __attribute__((address_space(1))) unsigned int*)g,
        (__attribute__((address_space(3))) unsigned int*)l, 16, 0, 0);
}

__device__ __forceinline__ void barrier_raw() {
    asm volatile("" ::: "memory");
    __builtin_amdgcn_s_barrier();
    asm volatile("" ::: "memory");
}

__device__ __forceinline__ void vmwait0() {
    asm volatile("s_waitcnt vmcnt(0)" ::: "memory");
}

__device__ __forceinline__ float gelu_fast(float u) {
    float z = 1.595769122f * u + 0.071354816f * u * u * u;
    return u / (1.f + __expf(-z));
}

// ---------------- weight convert: fp32 -> bf16, 4 elems/thread ----------------
__global__ __launch_bounds__(256) void f2b4(const float* __restrict__ in,
                                            unsigned short* __restrict__ out) {
    size_t i = ((size_t)blockIdx.x * 256 + threadIdx.x) * 4;
    float4 v = *(const float4*)(in + i);
    ushort4 o;
    o.x = f2bf(v.x); o.y = f2bf(v.y); o.z = f2bf(v.z); o.w = f2bf(v.w);
    *(ushort4*)(out + i) = o;
}

// ------------- transpose + convert: fp32 [R][C] -> bf16 [C][R] ---------------
__global__ __launch_bounds__(256) void transpose_f2b(const float* __restrict__ in,
                                                     unsigned short* __restrict__ out,
                                                     int R, int C) {
    __shared__ float tile[32][33];
    int r0 = blockIdx.y * 32, c0 = blockIdx.x * 32;
    int tx = threadIdx.x & 31, ty = threadIdx.x >> 5;
#pragma unroll
    for (int i = 0; i < 4; i++) {
        int r = ty + i * 8;
        tile[r][tx] = in[(size_t)(r0 + r) * C + c0 + tx];
    }
    __syncthreads();
#pragma unroll
    for (int i = 0; i < 4; i++) {
        int r = ty + i * 8;
        out[(size_t)(c0 + r) * R + r0 + tx] = f2bf(tile[tx][r]);
    }
}

// -------- ada modulation, split-K --------
__global__ __launch_bounds__(256) void ada_mod_part(const float* __restrict__ c,
                                                    const float* __restrict__ W,
                                                    float* __restrict__ partial) {
    __shared__ float sc[8 * 64];
    int kc = blockIdx.y * 64;
    for (int i = threadIdx.x; i < 512; i += 256) {
        int b = i >> 6, k = i & 63;
        float cv = c[b * 1024 + kc + k];
        sc[i] = cv / (1.f + __expf(-cv));
    }
    __syncthreads();
    int j = blockIdx.x * 256 + threadIdx.x;
    float acc[8] = {0, 0, 0, 0, 0, 0, 0, 0};
    for (int k = 0; k < 64; k++) {
        float w = W[(size_t)(kc + k) * 3072 + j];
#pragma unroll
        for (int b = 0; b < 8; b++) acc[b] += sc[b * 64 + k] * w;
    }
#pragma unroll
    for (int b = 0; b < 8; b++) partial[((size_t)blockIdx.y * 8 + b) * 3072 + j] = acc[b];
}

__global__ __launch_bounds__(256) void ada_reduce(const float* __restrict__ partial,
                                                  const float* __restrict__ bias,
                                                  float* __restrict__ out) {
    int idx = blockIdx.x * 256 + threadIdx.x;
    int b = idx / 3072;
    int jj = idx - b * 3072;
    float s = bias[jj];
#pragma unroll
    for (int ch = 0; ch < 16; ch++) s += partial[((size_t)ch * 8 + b) * 3072 + jj];
    out[idx] = s;
}

// -------- LN + adaLN modulate: fp32 row -> bf16 row --------
__global__ __launch_bounds__(256) void ln_mod_kernel(const float* __restrict__ x,
                                                     const float* __restrict__ gamma,
                                                     const float* __restrict__ beta,
                                                     const float* __restrict__ mods,
                                                     unsigned short* __restrict__ out) {
    int row = blockIdx.x;
    int b = row >> 10;
    float4 v = ((const float4*)(x + (size_t)row * 1024))[threadIdx.x];
    float s = v.x + v.y + v.z + v.w;
    float s2 = v.x * v.x + v.y * v.y + v.z * v.z + v.w * v.w;
#pragma unroll
    for (int d = 1; d < 64; d <<= 1) { s += __shfl_xor(s, d); s2 += __shfl_xor(s2, d); }
    __shared__ float red[8];
    int lane = threadIdx.x & 63, wid = threadIdx.x >> 6;
    if (lane == 0) { red[wid] = s; red[4 + wid] = s2; }
    __syncthreads();
    float S = red[0] + red[1] + red[2] + red[3];
    float S2 = red[4] + red[5] + red[6] + red[7];
    float mu = S * (1.f / 1024.f);
    float var = S2 * (1.f / 1024.f) - mu * mu;
    float rs = rsqrtf(var + 1e-6f);
    const float* mrow = mods + b * 3072;
    int j0 = threadIdx.x * 4;
    float hv[4] = {v.x, v.y, v.z, v.w};
    ushort4 o;
    unsigned short* op = (unsigned short*)&o;
#pragma unroll
    for (int i = 0; i < 4; i++) {
        int j = j0 + i;
        float hh = (hv[i] - mu) * rs * gamma[j] + beta[j];
        hh = hh * (1.f + mrow[1024 + j]) + mrow[j];
        op[i] = f2bf(hh);
    }
    *(ushort4*)(out + (size_t)row * 1024 + j0) = o;
}

// ============ wide-wave GEMM: BM=128, BN=256, BK=32, 256 thr (4 waves 1x4) ============
// Per-wave 128x64 (8x4 frags) -> LDS reads/MFMA = 0.375 (12 b128 per 32 MFMA),
// below the LDS-BW:matrix-pipe balance point.  LDS 48KB + ~180 VGPR ->
// 2 independent blocks/CU overlap each other's vmcnt/barrier stalls.
// 64B LDS rows, (row>>1)&3 16B-slot XOR (r8-measured 0 conflicts), source
// pre-swizzled for global_load_lds.  Stage next tile FIRST (full-tile cover).
// B-panel-pinned XCD map: bx = swz/ny (weight panel stays hot in XCD L2).
// EP: 0 = +bias -> bf16 (cols>=2048 write V^T to vt), 2 = gelu(acc+bias) -> bf16
template <int EP>
__global__ __launch_bounds__(256, 2) void gemmw(const unsigned short* __restrict__ A,
                                                const unsigned short* __restrict__ Bt,
                                                int N, int K, int ny,
                                                const float* __restrict__ bias,
                                                unsigned short* __restrict__ outb,
                                                unsigned short* __restrict__ vt) {
    constexpr int AE = 128 * 32;            // 4096 elems per A buffer (8KB)
    constexpr int BE = 256 * 32;            // 8192 elems per B buffer (16KB)
    extern __shared__ __align__(16) char smem[];
    __bf16* As = (__bf16*)smem;             // 2 x AE
    __bf16* Bs = As + 2 * AE;               // 2 x BE

    int tid = threadIdx.x, lane = tid & 63, wid = tid >> 6;   // 4 waves, wc = wid
    int t = lane & 15, g = lane >> 4;
    int xk2 = ((t >> 1) & 3) * 8;           // fragment-read slot XOR (elems)

    int nwg = gridDim.x, chunk = nwg >> 3;
    int swz = (blockIdx.x & 7) * chunk + (blockIdx.x >> 3);
    int bx = swz / ny, by = swz % ny;       // B-panel pinned per XCD
    int rowA0 = by * 128, colB0 = bx * 256;

    int rin = tid >> 2, cblk = tid & 3;
    int scol = (cblk ^ ((rin >> 1) & 3)) * 8;   // pre-swizzled source col (elems)

    auto stage = [&](int nb, int kt) {
        int k0 = kt << 5;
        gload16(A + (size_t)(rowA0 + rin) * K + k0 + scol, As + nb * AE + tid * 8);
        gload16(A + (size_t)(rowA0 + 64 + rin) * K + k0 + scol,
                As + nb * AE + 2048 + tid * 8);
#pragma unroll
        for (int sl = 0; sl < 4; sl++)
            gload16(Bt + (size_t)(colB0 + sl * 64 + rin) * K + k0 + scol,
                    Bs + nb * BE + sl * 2048 + tid * 8);
    };

    f32x4 acc[8][4];
#pragma unroll
    for (int m = 0; m < 8; m++)
#pragma unroll
        for (int n = 0; n < 4; n++) acc[m][n] = (f32x4){0.f, 0.f, 0.f, 0.f};

    stage(0, 0);
    vmwait0();
    barrier_raw();

    int NT = K >> 5;
#pragma unroll 2
    for (int kt = 0; kt < NT; ++kt) {
        const __bf16* Ac = As + (kt & 1) * AE;
        const __bf16* Bc = Bs + (kt & 1) * BE;
        bool more = (kt + 1) < NT;
        if (more) stage((kt & 1) ^ 1, kt + 1);   // full-tile latency cover

        bf16x8 b[4];
#pragma unroll
        for (int n = 0; n < 4; n++)
            b[n] = *(const bf16x8*)&Bc[(wid * 64 + n * 16 + t) * 32 + ((g * 8) ^ xk2)];

        __builtin_amdgcn_s_setprio(1);
#pragma unroll
        for (int mh = 0; mh < 2; mh++) {
            bf16x8 a[4];
#pragma unroll
            for (int m4 = 0; m4 < 4; m4++)
                a[m4] = *(const bf16x8*)&Ac[(mh * 64 + m4 * 16 + t) * 32 + ((g * 8) ^ xk2)];
#pragma unroll
            for (int m4 = 0; m4 < 4; m4++)
#pragma unroll
                for (int n = 0; n < 4; n++)
                    acc[mh * 4 + m4][n] =
                        __builtin_amdgcn_mfma_f32_16x16x32_bf16(a[m4], b[n], acc[mh * 4 + m4][n], 0, 0, 0);
        }
        __builtin_amdgcn_s_setprio(0);

        if (more) {
            vmwait0();
            barrier_raw();
        }
    }

    // ---- epilogue ----
    int col0 = colB0 + wid * 64;
    bool vpart = (EP == 0) && (colB0 >= 2048);
#pragma unroll
    for (int m = 0; m < 8; m++)
#pragma unroll
        for (int n = 0; n < 4; n++) {
            int col = col0 + n * 16 + t;
            if (EP == 0 && vpart) {
                int hcol = col - 2048;
                int hh = hcol >> 7, d = hcol & 127;
                int bb = rowA0 >> 10;
                int ntok = (rowA0 + m * 16 + g * 4) & 1023;
                float bs = bias[col];
                ushort4 vv;
                vv.x = f2bf(acc[m][n][0] + bs);
                vv.y = f2bf(acc[m][n][1] + bs);
                vv.z = f2bf(acc[m][n][2] + bs);
                vv.w = f2bf(acc[m][n][3] + bs);
                *(ushort4*)(vt + (((size_t)(bb * 8 + hh) * 128 + d) * 1024 + ntok)) = vv;
            } else {
#pragma unroll
                for (int r = 0; r < 4; r++) {
                    int row = rowA0 + m * 16 + g * 4 + r;
                    float v = acc[m][n][r];
                    if (EP == 0) {
                        outb[(size_t)row * N + col] = f2bf(v + bias[col]);
                    } else {
                        outb[(size_t)row * N + col] = f2bf(gelu_fast(v + bias[col]));
                    }
                }
            }
        }
}

// ============ occupancy-first GEMM (NF2): BM=128, BN=128, BK=32 ============
// 256 thr (4 waves 2x2), per-wave 64x64, LDS 32KB.
// EP: 1 = x+gate*(acc+bias) -> f32, 3 = outf += gate*(acc+bias)
template <int EP>
__global__ __launch_bounds__(256, 4) void gemmo(const unsigned short* __restrict__ A,
                                                const unsigned short* __restrict__ Bt,
                                                int N, int K, int nx,
                                                const float* __restrict__ bias,
                                                const float* __restrict__ xres,
                                                const float* __restrict__ mods,
                                                float* __restrict__ outf) {
    constexpr int AE = 128 * 32;
    constexpr int BE = 128 * 32;
    extern __shared__ __align__(16) char smem[];
    __bf16* As = (__bf16*)smem;
    __bf16* Bs = As + 2 * AE;

    int tid = threadIdx.x, lane = tid & 63, wid = tid >> 6;
    int wr = wid >> 1, wc = wid & 1;
    int t = lane & 15, g = lane >> 4;
    int xk2 = ((t >> 1) & 3) * 8;

    int nwg = gridDim.x, chunk = nwg >> 3;
    int swz = (blockIdx.x & 7) * chunk + (blockIdx.x >> 3);
    int bx = swz % nx, by = swz / nx;
    int rowA0 = by * 128, colB0 = bx * 128;

    int rin = tid >> 2, cblk = tid & 3;
    int scol = (cblk ^ ((rin >> 1) & 3)) * 8;

    auto stage = [&](int nb, int kt) {
        int k0 = kt << 5;
        gload16(A + (size_t)(rowA0 + rin) * K + k0 + scol, As + nb * AE + tid * 8);
        gload16(A + (size_t)(rowA0 + 64 + rin) * K + k0 + scol,
                As + nb * AE + 2048 + tid * 8);
        gload16(Bt + (size_t)(colB0 + rin) * K + k0 + scol, Bs + nb * BE + tid * 8);
        gload16(Bt + (size_t)(colB0 + 64 + rin) * K + k0 + scol,
                Bs + nb * BE + 2048 + tid * 8);
    };

    f32x4 acc[4][4];
#pragma unroll
    for (int m = 0; m < 4; m++)
#pragma unroll
        for (int n = 0; n < 4; n++) acc[m][n] = (f32x4){0.f, 0.f, 0.f, 0.f};

    stage(0, 0);
    vmwait0();
    barrier_raw();

    int NT = K >> 5;
#pragma unroll 2
    for (int kt = 0; kt < NT; ++kt) {
        const __bf16* Ac = As + (kt & 1) * AE;
        const __bf16* Bc = Bs + (kt & 1) * BE;
        bool more = (kt + 1) < NT;
        if (more) stage((kt & 1) ^ 1, kt + 1);

        bf16x8 a[4], b[4];
#pragma unroll
        for (int m = 0; m < 4; m++)
            a[m] = *(const bf16x8*)&Ac[(wr * 64 + m * 16 + t) * 32 + ((g * 8) ^ xk2)];
#pragma unroll
        for (int n = 0; n < 4; n++)
            b[n] = *(const bf16x8*)&Bc[(wc * 64 + n * 16 + t) * 32 + ((g * 8) ^ xk2)];

        __builtin_amdgcn_s_setprio(1);
#pragma unroll
        for (int m = 0; m < 4; m++)
#pragma unroll
            for (int n = 0; n < 4; n++)
                acc[m][n] = __builtin_amdgcn_mfma_f32_16x16x32_bf16(a[m], b[n], acc[m][n], 0, 0, 0);
        __builtin_amdgcn_s_setprio(0);

        if (more) {
            vmwait0();
            barrier_raw();
        }
    }

    int row0 = rowA0 + wr * 64, col0 = colB0 + wc * 64;
#pragma unroll
    for (int m = 0; m < 4; m++)
#pragma unroll
        for (int n = 0; n < 4; n++) {
            int col = col0 + n * 16 + t;
#pragma unroll
            for (int r = 0; r < 4; r++) {
                int row = row0 + m * 16 + g * 4 + r;
                float v = acc[m][n][r];
                int bb = row >> 10;
                float gt = mods[bb * 3072 + 2048 + col];
                if (EP == 1) {
                    outf[(size_t)row * 1024 + col] =
                        xres[(size_t)row * 1024 + col] + gt * (v + bias[col]);
                } else {
                    outf[(size_t)row * 1024 + col] += gt * (v + bias[col]);
                }
            }
        }
}

// ======== flash attention, swapped-QK^T in-register softmax ========
__global__ __launch_bounds__(512, 4) void attn_kernel(const unsigned short* __restrict__ qkv,
                                                      const unsigned short* __restrict__ vt,
                                                      unsigned short* __restrict__ o) {
    extern __shared__ __align__(16) char asmem[];
    __bf16* Ks = (__bf16*)asmem;
    __bf16* Vts = Ks + 2 * 64 * 128;

    int bid = blockIdx.x;
    int logical = (bid & 7) * 64 + (bid >> 3);
    int q0 = (logical & 7) * 128;
    int bh = logical >> 3;
    int b = bh >> 3, h = bh & 7;
    int tid = threadIdx.x, lane = tid & 63, w = tid >> 6;
    int t = lane & 15, g = lane >> 4;
    int swzt = (t & 7) << 4;

    const unsigned short* qbase = qkv + (size_t)(b * 1024) * 3072 + h * 128;
    int qrow = q0 + w * 16 + t;
    bf16x8 qf[4];
#pragma unroll
    for (int ks = 0; ks < 4; ks++)
        qf[ks] = *(const bf16x8*)(qbase + (size_t)qrow * 3072 + ks * 32 + g * 8);

    f32x4 Oa[8];
#pragma unroll
    for (int n = 0; n < 8; n++) Oa[n] = (f32x4){0.f, 0.f, 0.f, 0.f};
    float m_r = -1e30f, l_r = 0.f;
    const float scale = 0.08838834764831845f;

    int krow = tid >> 4;
    int ksrc = (((tid & 15) * 16) ^ ((krow & 7) << 4)) >> 1;
    int vrow = tid >> 3;
    int vsrc = (((tid & 7) * 16) ^ ((vrow & 7) << 4)) >> 1;
    const unsigned short* vtg = vt + (size_t)bh * 128 * 1024;

    auto stage = [&](int buf, int kv0) {
        const unsigned short* kb = qkv + (size_t)(b * 1024 + kv0) * 3072 + 1024 + h * 128;
#pragma unroll
        for (int cc = 0; cc < 2; cc++) {
            gload16(kb + (size_t)(cc * 32 + krow) * 3072 + ksrc,
                    (void*)(Ks + buf * 8192 + cc * 4096 + tid * 8));
            gload16(vtg + (size_t)(cc * 64 + vrow) * 1024 + kv0 + vsrc,
                    (void*)(Vts + buf * 8192 + cc * 4096 + tid * 8));
        }
    };

    stage(0, 0);
    vmwait0();
    barrier_raw();

#pragma unroll 1
    for (int tile = 0; tile < 16; ++tile) {
        int cur = tile & 1;
        bool more = tile < 15;
        if (more) stage(cur ^ 1, (tile + 1) * 64);
        const __bf16* Kc = Ks + cur * 8192;
        const __bf16* Vc = Vts + cur * 8192;

        f32x4 St[4];
#pragma unroll
        for (int n = 0; n < 4; n++) St[n] = (f32x4){0.f, 0.f, 0.f, 0.f};
        __builtin_amdgcn_s_setprio(1);
#pragma unroll
        for (int ks = 0; ks < 4; ks++) {
#pragma unroll
            for (int n = 0; n < 4; n++) {
                bf16x8 kf = *(const bf16x8*)&Kc[(n * 16 + t) * 128 + (((ks * 64 + g * 16) ^ swzt) >> 1)];
                St[n] = __builtin_amdgcn_mfma_f32_16x16x32_bf16(kf, qf[ks], St[n], 0, 0, 0);
            }
        }
        __builtin_amdgcn_s_setprio(0);

        float mx = -1e30f;
#pragma unroll
        for (int n = 0; n < 4; n++)
#pragma unroll
            for (int r = 0; r < 4; r++) mx = fmaxf(mx, St[n][r]);
        mx *= scale;
        mx = fmaxf(mx, __shfl_xor(mx, 16));
        mx = fmaxf(mx, __shfl_xor(mx, 32));
        float mn = fmaxf(m_r, mx);
        float alpha = __expf(m_r - mn);
        m_r = mn;
        float p[4][4];
        float rs = 0.f;
#pragma unroll
        for (int n = 0; n < 4; n++)
#pragma unroll
            for (int r = 0; r < 4; r++) {
                float pv = __expf(St[n][r] * scale - mn);
                p[n][r] = pv;
                rs += pv;
            }
        rs += __shfl_xor(rs, 16);
        rs += __shfl_xor(rs, 32);
        l_r = l_r * alpha + rs;

        unsigned P01[4], P23[4];
#pragma unroll
        for (int n = 0; n < 4; n++) {
            P01[n] = (unsigned)f2bf(p[n][0]) | ((unsigned)f2bf(p[n][1]) << 16);
            P23[n] = (unsigned)f2bf(p[n][2]) | ((unsigned)f2bf(p[n][3]) << 16);
        }

#pragma unroll
        for (int r = 0; r < 4; r++) {
            float ar = __shfl(alpha, (lane & 48) + g * 4 + r);
#pragma unroll
            for (int n2 = 0; n2 < 8; n2++) Oa[n2][r] *= ar;
        }

#pragma unroll
        for (int ks2 = 0; ks2 < 2; ks2++) {
            int e = ks2 * 2, od = ks2 * 2 + 1;
            unsigned s16a = (g < 2) ? P01[e] : P01[od];
            unsigned s16b = (g < 2) ? P23[e] : P23[od];
            unsigned s32a = (g & 1) ? P01[e] : P01[od];
            unsigned s32b = (g & 1) ? P23[e] : P23[od];
            unsigned s48a = (g >= 2) ? P01[e] : P01[od];
            unsigned s48b = (g >= 2) ? P23[e] : P23[od];
            unsigned r16a = __shfl_xor(s16a, 16), r16b = __shfl_xor(s16b, 16);
            unsigned r32a = __shfl_xor(s32a, 32), r32b = __shfl_xor(s32b, 32);
            unsigned r48a = __shfl_xor(s48a, 48), r48b = __shfl_xor(s48b, 48);
            union { unsigned u[4]; bf16x8 v; } pa;
            pa.u[0] = (g == 0) ? P01[e] : (g == 1) ? r48a : (g == 2) ? r32a : r16a;
            pa.u[1] = (g == 0) ? P23[e] : (g == 1) ? r48b : (g == 2) ? r32b : r16b;
            pa.u[2] = (g == 0) ? r16a : (g == 1) ? r32a : (g == 2) ? r48a : P01[od];
            pa.u[3] = (g == 0) ? r16b : (g == 1) ? r32b : (g == 2) ? r48b : P23[od];
            __builtin_amdgcn_s_setprio(1);
#pragma unroll
            for (int n2 = 0; n2 < 8; n2++) {
                bf16x8 vf = *(const bf16x8*)&Vc[(n2 * 16 + t) * 64 + (((ks2 * 64 + g * 16) ^ swzt) >> 1)];
                Oa[n2] = __builtin_amdgcn_mfma_f32_16x16x32_bf16(pa.v, vf, Oa[n2], 0, 0, 0);
            }
            __builtin_amdgcn_s_setprio(0);
        }

        if (more) {
            vmwait0();
            barrier_raw();
        }
    }

#pragma unroll
    for (int r = 0; r < 4; r++) {
        float lq = __shfl(l_r, (lane & 48) + g * 4 + r);
        float inv = 1.f / lq;
        int orow = q0 + w * 16 + g * 4 + r;
#pragma unroll
        for (int n2 = 0; n2 < 8; n2++)
            o[(size_t)(b * 1024 + orow) * 1024 + h * 128 + n2 * 16 + t] = f2bf(Oa[n2][r] * inv);
    }
}

extern "C" void kernel_launch(void* const* d_in, const int* in_sizes, int n_in,
                              void* d_out, int out_size, void* d_ws, size_t ws_size,
                              hipStream_t stream) {
    const float* x          = (const float*)d_in[0];
    const float* c          = (const float*)d_in[1];
    const float* m_ada_w    = (const float*)d_in[2];
    const float* m_ada_b    = (const float*)d_in[3];
    const float* m_norm_g   = (const float*)d_in[4];
    const float* m_norm_b   = (const float*)d_in[5];
    const float* in_proj_w  = (const float*)d_in[6];
    const float* in_proj_b  = (const float*)d_in[7];
    const float* out_proj_w = (const float*)d_in[8];
    const float* out_proj_b = (const float*)d_in[9];
    const float* f_ada_w    = (const float*)d_in[10];
    const float* f_ada_b    = (const float*)d_in[11];
    const float* f_norm_g   = (const float*)d_in[12];
    const float* f_norm_b   = (const float*)d_in[13];
    const float* w1         = (const float*)d_in[14];
    const float* b1         = (const float*)d_in[15];
    const float* w2         = (const float*)d_in[16];
    const float* b2         = (const float*)d_in[17];
    float* out = (float*)d_out;
    char* ws = (char*)d_ws;

    unsigned short* Wq   = (unsigned short*)(ws + 0);          // 3072x1024 bf16
    unsigned short* Wo   = (unsigned short*)(ws + 6291456);    // 1024x1024
    unsigned short* vt   = (unsigned short*)(ws + 8388608);    // 64x128x1024 (later W1t/W2t)
    unsigned short* W1t  = (unsigned short*)(ws + 8388608);    // 4096x1024
    unsigned short* W2t  = (unsigned short*)(ws + 16777216);   // 1024x4096
    float*          modm = (float*)(ws + 25165824);            // 8x3072
    float*          modf = (float*)(ws + 25264128);            // 8x3072
    unsigned short* hbuf = (unsigned short*)(ws + 25362432);   // 8192x1024
    float*          part = (float*)(ws + 25362432);            // ada partials (hbuf region)
    float*          part2= (float*)(ws + 25362432 + 2097152);
    unsigned short* qkv  = (unsigned short*)(ws + 42139648);   // 8192x3072
    unsigned short* obuf = (unsigned short*)(ws + 92471296);   // 8192x1024
    unsigned short* h2   = (unsigned short*)(ws + 42139648);   // 8192x4096 (aliases qkv+obuf)

    hipFuncSetAttribute((const void*)&gemmw<0>, hipFuncAttributeMaxDynamicSharedMemorySize, 49152);
    hipFuncSetAttribute((const void*)&gemmw<2>, hipFuncAttributeMaxDynamicSharedMemorySize, 49152);
    hipFuncSetAttribute((const void*)&gemmo<1>, hipFuncAttributeMaxDynamicSharedMemorySize, 32768);
    hipFuncSetAttribute((const void*)&gemmo<3>, hipFuncAttributeMaxDynamicSharedMemorySize, 32768);
    hipFuncSetAttribute((const void*)&attn_kernel, hipFuncAttributeMaxDynamicSharedMemorySize, 65536);

    hipLaunchKernelGGL(ada_mod_part, dim3(12, 16), dim3(256), 0, stream, c, m_ada_w, part);
    hipLaunchKernelGGL(ada_mod_part, dim3(12, 16), dim3(256), 0, stream, c, f_ada_w, part2);
    hipLaunchKernelGGL(ada_reduce, dim3(96), dim3(256), 0, stream, part, m_ada_b, modm);
    hipLaunchKernelGGL(ada_reduce, dim3(96), dim3(256), 0, stream, part2, f_ada_b, modf);

    hipLaunchKernelGGL(f2b4, dim3(3072), dim3(256), 0, stream, in_proj_w, Wq);
    hipLaunchKernelGGL(f2b4, dim3(1024), dim3(256), 0, stream, out_proj_w, Wo);

    hipLaunchKernelGGL(ln_mod_kernel, dim3(8192), dim3(256), 0, stream, x, m_norm_g, m_norm_b, modm, hbuf);
    // qkv: 64 row-panels x 12 cols = 768 blocks; V cols write vt directly
    hipLaunchKernelGGL(HIP_KERNEL_NAME(gemmw<0>), dim3(768), dim3(256), 49152, stream,
                       hbuf, Wq, 3072, 1024, 64, in_proj_b, qkv, vt);
    hipLaunchKernelGGL(attn_kernel, dim3(512), dim3(512), 65536, stream, qkv, vt, obuf);
    // out-proj: 64 x 8 = 512 blocks
    hipLaunchKernelGGL(HIP_KERNEL_NAME(gemmo<1>), dim3(512), dim3(256), 32768, stream,
                       obuf, Wo, 1024, 1024, 8, out_proj_b, x, modm, out);

    hipLaunchKernelGGL(transpose_f2b, dim3(128, 32), dim3(256), 0, stream, w1, W1t, 1024, 4096);
    hipLaunchKernelGGL(transpose_f2b, dim3(32, 128), dim3(256), 0, stream, w2, W2t, 4096, 1024);

    hipLaunchKernelGGL(ln_mod_kernel, dim3(8192), dim3(256), 0, stream, out, f_norm_g, f_norm_b, modf, hbuf);
    // FF1: 64 x 16 = 1024 blocks
    hipLaunchKernelGGL(HIP_KERNEL_NAME(gemmw<2>), dim3(1024), dim3(256), 49152, stream,
                       hbuf, W1t, 4096, 1024, 64, b1, h2, (unsigned short*)nullptr);
    // FF2: K=4096, 64 x 8 = 512 blocks
    hipLaunchKernelGGL(HIP_KERNEL_NAME(gemmo<3>), dim3(512), dim3(256), 32768, stream,
                       h2, W2t, 1024, 4096, 8, b2, (const float*)nullptr, modf, out);
}

// Round 10
// 386.592 us; speedup vs baseline: 1.0196x; 1.0196x over previous
//
#include <hip/hip_runtime.h>

typedef __bf16 bf16x8 __attribute__((ext_vector_type(8)));
typedef float f32x4 __attribute__((ext_vector_type(4)));

__device__ __forceinline__ unsigned short f2bf(float f) {
    unsigned int u = __float_as_uint(f);
    unsigned int r = (u + 0x7FFFu + ((u >> 16) & 1u)) >> 16;
    return (unsigned short)r;
}

__device__ __forceinline__ void gload16(const void* g, void* l) {
    __builtin_amdgcn_global_load_lds(
        (const __attribute__((address_space(1))) unsigned int*)g,
        (__attribute__((address_space(3))) unsigned int*)l, 16, 0, 0);
}

__device__ __forceinline__ void barrier_raw() {
    asm volatile("" ::: "memory");
    __builtin_amdgcn_s_barrier();
    asm volatile("" ::: "memory");
}

__device__ __forceinline__ void vmwait0() {
    asm volatile("s_waitcnt vmcnt(0)" ::: "memory");
}

__device__ __forceinline__ float gelu_fast(float u) {
    float z = 1.595769122f * u + 0.071354816f * u * u * u;
    return u / (1.f + __expf(-z));
}

// ---------------- weight convert: fp32 -> bf16, 4 elems/thread ----------------
__global__ __launch_bounds__(256) void f2b4(const float* __restrict__ in,
                                            unsigned short* __restrict__ out) {
    size_t i = ((size_t)blockIdx.x * 256 + threadIdx.x) * 4;
    float4 v = *(const float4*)(in + i);
    ushort4 o;
    o.x = f2bf(v.x); o.y = f2bf(v.y); o.z = f2bf(v.z); o.w = f2bf(v.w);
    *(ushort4*)(out + i) = o;
}

// ------------- transpose + convert: fp32 [R][C] -> bf16 [C][R] ---------------
__global__ __launch_bounds__(256) void transpose_f2b(const float* __restrict__ in,
                                                     unsigned short* __restrict__ out,
                                                     int R, int C) {
    __shared__ float tile[32][33];
    int r0 = blockIdx.y * 32, c0 = blockIdx.x * 32;
    int tx = threadIdx.x & 31, ty = threadIdx.x >> 5;
#pragma unroll
    for (int i = 0; i < 4; i++) {
        int r = ty + i * 8;
        tile[r][tx] = in[(size_t)(r0 + r) * C + c0 + tx];
    }
    __syncthreads();
#pragma unroll
    for (int i = 0; i < 4; i++) {
        int r = ty + i * 8;
        out[(size_t)(c0 + r) * R + r0 + tx] = f2bf(tile[tx][r]);
    }
}

// -------- ada modulation, split-K --------
__global__ __launch_bounds__(256) void ada_mod_part(const float* __restrict__ c,
                                                    const float* __restrict__ W,
                                                    float* __restrict__ partial) {
    __shared__ float sc[8 * 64];
    int kc = blockIdx.y * 64;
    for (int i = threadIdx.x; i < 512; i += 256) {
        int b = i >> 6, k = i & 63;
        float cv = c[b * 1024 + kc + k];
        sc[i] = cv / (1.f + __expf(-cv));
    }
    __syncthreads();
    int j = blockIdx.x * 256 + threadIdx.x;
    float acc[8] = {0, 0, 0, 0, 0, 0, 0, 0};
    for (int k = 0; k < 64; k++) {
        float w = W[(size_t)(kc + k) * 3072 + j];
#pragma unroll
        for (int b = 0; b < 8; b++) acc[b] += sc[b * 64 + k] * w;
    }
#pragma unroll
    for (int b = 0; b < 8; b++) partial[((size_t)blockIdx.y * 8 + b) * 3072 + j] = acc[b];
}

__global__ __launch_bounds__(256) void ada_reduce(const float* __restrict__ partial,
                                                  const float* __restrict__ bias,
                                                  float* __restrict__ out) {
    int idx = blockIdx.x * 256 + threadIdx.x;
    int b = idx / 3072;
    int jj = idx - b * 3072;
    float s = bias[jj];
#pragma unroll
    for (int ch = 0; ch < 16; ch++) s += partial[((size_t)ch * 8 + b) * 3072 + jj];
    out[idx] = s;
}

// -------- LN + adaLN modulate: fp32 row -> bf16 row --------
__global__ __launch_bounds__(256) void ln_mod_kernel(const float* __restrict__ x,
                                                     const float* __restrict__ gamma,
                                                     const float* __restrict__ beta,
                                                     const float* __restrict__ mods,
                                                     unsigned short* __restrict__ out) {
    int row = blockIdx.x;
    int b = row >> 10;
    float4 v = ((const float4*)(x + (size_t)row * 1024))[threadIdx.x];
    float s = v.x + v.y + v.z + v.w;
    float s2 = v.x * v.x + v.y * v.y + v.z * v.z + v.w * v.w;
#pragma unroll
    for (int d = 1; d < 64; d <<= 1) { s += __shfl_xor(s, d); s2 += __shfl_xor(s2, d); }
    __shared__ float red[8];
    int lane = threadIdx.x & 63, wid = threadIdx.x >> 6;
    if (lane == 0) { red[wid] = s; red[4 + wid] = s2; }
    __syncthreads();
    float S = red[0] + red[1] + red[2] + red[3];
    float S2 = red[4] + red[5] + red[6] + red[7];
    float mu = S * (1.f / 1024.f);
    float var = S2 * (1.f / 1024.f) - mu * mu;
    float rs = rsqrtf(var + 1e-6f);
    const float* mrow = mods + b * 3072;
    int j0 = threadIdx.x * 4;
    float hv[4] = {v.x, v.y, v.z, v.w};
    ushort4 o;
    unsigned short* op = (unsigned short*)&o;
#pragma unroll
    for (int i = 0; i < 4; i++) {
        int j = j0 + i;
        float hh = (hv[i] - mu) * rs * gamma[j] + beta[j];
        hh = hh * (1.f + mrow[1024 + j]) + mrow[j];
        op[i] = f2bf(hh);
    }
    *(ushort4*)(out + (size_t)row * 1024 + j0) = o;
}

// ============ depth-2 prefetch wide-wave GEMM: BM=128, BN=256, BK=32 ============
// 256 thr (4 waves 1x4), per-wave 128x64.  LDS = 3 bufs x 24KB = 72KB
// (2 blocks/CU).  Iter kt: issue stage(kt+2) FIRST -> ds_read cur -> MFMA ->
// vmcnt(6) [kt+1 complete; kt+2's 6 loads stay in flight, ~2 steps of cover]
// -> barrier.  64B LDS rows, (row>>1)&3 16B-slot XOR (0 conflicts measured),
// source pre-swizzled for global_load_lds.  Chunked-XCD col-fast map (r8's
// 74MB-FETCH variant).
// EP: 0 = +bias -> bf16 (cols>=2048 write V^T to vt), 2 = gelu(acc+bias) -> bf16
template <int EP>
__global__ __launch_bounds__(256, 2) void gemmw(const unsigned short* __restrict__ A,
                                                const unsigned short* __restrict__ Bt,
                                                int N, int K, int nx,
                                                const float* __restrict__ bias,
                                                unsigned short* __restrict__ outb,
                                                unsigned short* __restrict__ vt) {
    constexpr int AE = 128 * 32;            // 4096 elems per A buffer (8KB)
    constexpr int BE = 256 * 32;            // 8192 elems per B buffer (16KB)
    extern __shared__ __align__(16) char smem[];
    __bf16* As = (__bf16*)smem;             // 3 x AE
    __bf16* Bs = As + 3 * AE;               // 3 x BE

    int tid = threadIdx.x, lane = tid & 63, wid = tid >> 6;   // 4 waves, wc = wid
    int t = lane & 15, g = lane >> 4;
    int xk2 = ((t >> 1) & 3) * 8;           // fragment-read slot XOR (elems)

    int nwg = gridDim.x, chunk = nwg >> 3;
    int swz = (blockIdx.x & 7) * chunk + (blockIdx.x >> 3);
    int bx = swz % nx, by = swz / nx;       // col-fast (r8 map, FETCH-verified)
    int rowA0 = by * 128, colB0 = bx * 256;

    int rin = tid >> 2, cblk = tid & 3;
    int scol = (cblk ^ ((rin >> 1) & 3)) * 8;   // pre-swizzled source col (elems)

    auto stage = [&](int nb, int kt) {          // 6 gload16
        int k0 = kt << 5;
        gload16(A + (size_t)(rowA0 + rin) * K + k0 + scol, As + nb * AE + tid * 8);
        gload16(A + (size_t)(rowA0 + 64 + rin) * K + k0 + scol,
                As + nb * AE + 2048 + tid * 8);
#pragma unroll
        for (int sl = 0; sl < 4; sl++)
            gload16(Bt + (size_t)(colB0 + sl * 64 + rin) * K + k0 + scol,
                    Bs + nb * BE + sl * 2048 + tid * 8);
    };

    f32x4 acc[8][4];
#pragma unroll
    for (int m = 0; m < 8; m++)
#pragma unroll
        for (int n = 0; n < 4; n++) acc[m][n] = (f32x4){0.f, 0.f, 0.f, 0.f};

    int NT = K >> 5;
    stage(0, 0);
    if (NT > 1) {
        stage(1, 1);
        asm volatile("s_waitcnt vmcnt(6)" ::: "memory");   // tile0 complete
    } else {
        vmwait0();
    }
    barrier_raw();

    int cur = 0, tgt = 2;
#pragma unroll 1
    for (int kt = 0; kt < NT; ++kt) {
        bool deep = (kt + 2) < NT;
        bool more = (kt + 1) < NT;
        if (deep) stage(tgt, kt + 2);        // issue early: ~2 steps of cover
        const __bf16* Ac = As + cur * AE;
        const __bf16* Bc = Bs + cur * BE;

        bf16x8 b[4];
#pragma unroll
        for (int n = 0; n < 4; n++)
            b[n] = *(const bf16x8*)&Bc[(wid * 64 + n * 16 + t) * 32 + ((g * 8) ^ xk2)];

        __builtin_amdgcn_s_setprio(1);
#pragma unroll
        for (int mh = 0; mh < 2; mh++) {
            bf16x8 a[4];
#pragma unroll
            for (int m4 = 0; m4 < 4; m4++)
                a[m4] = *(const bf16x8*)&Ac[(mh * 64 + m4 * 16 + t) * 32 + ((g * 8) ^ xk2)];
#pragma unroll
            for (int m4 = 0; m4 < 4; m4++)
#pragma unroll
                for (int n = 0; n < 4; n++)
                    acc[mh * 4 + m4][n] =
                        __builtin_amdgcn_mfma_f32_16x16x32_bf16(a[m4], b[n], acc[mh * 4 + m4][n], 0, 0, 0);
        }
        __builtin_amdgcn_s_setprio(0);

        if (more) {
            if (deep) {
                asm volatile("s_waitcnt vmcnt(6)" ::: "memory");  // kt+1 complete
            } else {
                vmwait0();
            }
            barrier_raw();
        }
        cur = (cur == 2) ? 0 : cur + 1;
        tgt = (tgt == 2) ? 0 : tgt + 1;
    }

    // ---- epilogue ----
    int col0 = colB0 + wid * 64;
    bool vpart = (EP == 0) && (colB0 >= 2048);
#pragma unroll
    for (int m = 0; m < 8; m++)
#pragma unroll
        for (int n = 0; n < 4; n++) {
            int col = col0 + n * 16 + t;
            if (EP == 0 && vpart) {
                int hcol = col - 2048;
                int hh = hcol >> 7, d = hcol & 127;
                int bb = rowA0 >> 10;
                int ntok = (rowA0 + m * 16 + g * 4) & 1023;
                float bs = bias[col];
                ushort4 vv;
                vv.x = f2bf(acc[m][n][0] + bs);
                vv.y = f2bf(acc[m][n][1] + bs);
                vv.z = f2bf(acc[m][n][2] + bs);
                vv.w = f2bf(acc[m][n][3] + bs);
                *(ushort4*)(vt + (((size_t)(bb * 8 + hh) * 128 + d) * 1024 + ntok)) = vv;
            } else {
#pragma unroll
                for (int r = 0; r < 4; r++) {
                    int row = rowA0 + m * 16 + g * 4 + r;
                    float v = acc[m][n][r];
                    if (EP == 0) {
                        outb[(size_t)row * N + col] = f2bf(v + bias[col]);
                    } else {
                        outb[(size_t)row * N + col] = f2bf(gelu_fast(v + bias[col]));
                    }
                }
            }
        }
}

// ============ depth-2 prefetch GEMM (NF2): BM=128, BN=128, BK=32 ============
// 256 thr (4 waves 2x2), per-wave 64x64, LDS = 3 x 16KB = 48KB (3 blocks/CU).
// EP: 1 = x+gate*(acc+bias) -> f32, 3 = outf += gate*(acc+bias)
template <int EP>
__global__ __launch_bounds__(256, 4) void gemmo(const unsigned short* __restrict__ A,
                                                const unsigned short* __restrict__ Bt,
                                                int N, int K, int nx,
                                                const float* __restrict__ bias,
                                                const float* __restrict__ xres,
                                                const float* __restrict__ mods,
                                                float* __restrict__ outf) {
    constexpr int AE = 128 * 32;
    constexpr int BE = 128 * 32;
    extern __shared__ __align__(16) char smem[];
    __bf16* As = (__bf16*)smem;             // 3 x AE
    __bf16* Bs = As + 3 * AE;               // 3 x BE

    int tid = threadIdx.x, lane = tid & 63, wid = tid >> 6;
    int wr = wid >> 1, wc = wid & 1;
    int t = lane & 15, g = lane >> 4;
    int xk2 = ((t >> 1) & 3) * 8;

    int nwg = gridDim.x, chunk = nwg >> 3;
    int swz = (blockIdx.x & 7) * chunk + (blockIdx.x >> 3);
    int bx = swz % nx, by = swz / nx;
    int rowA0 = by * 128, colB0 = bx * 128;

    int rin = tid >> 2, cblk = tid & 3;
    int scol = (cblk ^ ((rin >> 1) & 3)) * 8;

    auto stage = [&](int nb, int kt) {          // 4 gload16
        int k0 = kt << 5;
        gload16(A + (size_t)(rowA0 + rin) * K + k0 + scol, As + nb * AE + tid * 8);
        gload16(A + (size_t)(rowA0 + 64 + rin) * K + k0 + scol,
                As + nb * AE + 2048 + tid * 8);
        gload16(Bt + (size_t)(colB0 + rin) * K + k0 + scol, Bs + nb * BE + tid * 8);
        gload16(Bt + (size_t)(colB0 + 64 + rin) * K + k0 + scol,
                Bs + nb * BE + 2048 + tid * 8);
    };

    f32x4 acc[4][4];
#pragma unroll
    for (int m = 0; m < 4; m++)
#pragma unroll
        for (int n = 0; n < 4; n++) acc[m][n] = (f32x4){0.f, 0.f, 0.f, 0.f};

    int NT = K >> 5;
    stage(0, 0);
    if (NT > 1) {
        stage(1, 1);
        asm volatile("s_waitcnt vmcnt(4)" ::: "memory");
    } else {
        vmwait0();
    }
    barrier_raw();

    int cur = 0, tgt = 2;
#pragma unroll 1
    for (int kt = 0; kt < NT; ++kt) {
        bool deep = (kt + 2) < NT;
        bool more = (kt + 1) < NT;
        if (deep) stage(tgt, kt + 2);
        const __bf16* Ac = As + cur * AE;
        const __bf16* Bc = Bs + cur * BE;

        bf16x8 a[4], b[4];
#pragma unroll
        for (int m = 0; m < 4; m++)
            a[m] = *(const bf16x8*)&Ac[(wr * 64 + m * 16 + t) * 32 + ((g * 8) ^ xk2)];
#pragma unroll
        for (int n = 0; n < 4; n++)
            b[n] = *(const bf16x8*)&Bc[(wc * 64 + n * 16 + t) * 32 + ((g * 8) ^ xk2)];

        __builtin_amdgcn_s_setprio(1);
#pragma unroll
        for (int m = 0; m < 4; m++)
#pragma unroll
            for (int n = 0; n < 4; n++)
                acc[m][n] = __builtin_amdgcn_mfma_f32_16x16x32_bf16(a[m], b[n], acc[m][n], 0, 0, 0);
        __builtin_amdgcn_s_setprio(0);

        if (more) {
            if (deep) {
                asm volatile("s_waitcnt vmcnt(4)" ::: "memory");
            } else {
                vmwait0();
            }
            barrier_raw();
        }
        cur = (cur == 2) ? 0 : cur + 1;
        tgt = (tgt == 2) ? 0 : tgt + 1;
    }

    int row0 = rowA0 + wr * 64, col0 = colB0 + wc * 64;
#pragma unroll
    for (int m = 0; m < 4; m++)
#pragma unroll
        for (int n = 0; n < 4; n++) {
            int col = col0 + n * 16 + t;
#pragma unroll
            for (int r = 0; r < 4; r++) {
                int row = row0 + m * 16 + g * 4 + r;
                float v = acc[m][n][r];
                int bb = row >> 10;
                float gt = mods[bb * 3072 + 2048 + col];
                if (EP == 1) {
                    outf[(size_t)row * 1024 + col] =
                        xres[(size_t)row * 1024 + col] + gt * (v + bias[col]);
                } else {
                    outf[(size_t)row * 1024 + col] += gt * (v + bias[col]);
                }
            }
        }
}

// ======== flash attention, swapped-QK^T in-register softmax ========
__global__ __launch_bounds__(512, 4) void attn_kernel(const unsigned short* __restrict__ qkv,
                                                      const unsigned short* __restrict__ vt,
                                                      unsigned short* __restrict__ o) {
    extern __shared__ __align__(16) char asmem[];
    __bf16* Ks = (__bf16*)asmem;
    __bf16* Vts = Ks + 2 * 64 * 128;

    int bid = blockIdx.x;
    int logical = (bid & 7) * 64 + (bid >> 3);
    int q0 = (logical & 7) * 128;
    int bh = logical >> 3;
    int b = bh >> 3, h = bh & 7;
    int tid = threadIdx.x, lane = tid & 63, w = tid >> 6;
    int t = lane & 15, g = lane >> 4;
    int swzt = (t & 7) << 4;

    const unsigned short* qbase = qkv + (size_t)(b * 1024) * 3072 + h * 128;
    int qrow = q0 + w * 16 + t;
    bf16x8 qf[4];
#pragma unroll
    for (int ks = 0; ks < 4; ks++)
        qf[ks] = *(const bf16x8*)(qbase + (size_t)qrow * 3072 + ks * 32 + g * 8);

    f32x4 Oa[8];
#pragma unroll
    for (int n = 0; n < 8; n++) Oa[n] = (f32x4){0.f, 0.f, 0.f, 0.f};
    float m_r = -1e30f, l_r = 0.f;
    const float scale = 0.08838834764831845f;

    int krow = tid >> 4;
    int ksrc = (((tid & 15) * 16) ^ ((krow & 7) << 4)) >> 1;
    int vrow = tid >> 3;
    int vsrc = (((tid & 7) * 16) ^ ((vrow & 7) << 4)) >> 1;
    const unsigned short* vtg = vt + (size_t)bh * 128 * 1024;

    auto stage = [&](int buf, int kv0) {
        const unsigned short* kb = qkv + (size_t)(b * 1024 + kv0) * 3072 + 1024 + h * 128;
#pragma unroll
        for (int cc = 0; cc < 2; cc++) {
            gload16(kb + (size_t)(cc * 32 + krow) * 3072 + ksrc,
                    (void*)(Ks + buf * 8192 + cc * 4096 + tid * 8));
            gload16(vtg + (size_t)(cc * 64 + vrow) * 1024 + kv0 + vsrc,
                    (void*)(Vts + buf * 8192 + cc * 4096 + tid * 8));
        }
    };

    stage(0, 0);
    vmwait0();
    barrier_raw();

#pragma unroll 1
    for (int tile = 0; tile < 16; ++tile) {
        int cur = tile & 1;
        bool more = tile < 15;
        if (more) stage(cur ^ 1, (tile + 1) * 64);
        const __bf16* Kc = Ks + cur * 8192;
        const __bf16* Vc = Vts + cur * 8192;

        f32x4 St[4];
#pragma unroll
        for (int n = 0; n < 4; n++) St[n] = (f32x4){0.f, 0.f, 0.f, 0.f};
        __builtin_amdgcn_s_setprio(1);
#pragma unroll
        for (int ks = 0; ks < 4; ks++) {
#pragma unroll
            for (int n = 0; n < 4; n++) {
                bf16x8 kf = *(const bf16x8*)&Kc[(n * 16 + t) * 128 + (((ks * 64 + g * 16) ^ swzt) >> 1)];
                St[n] = __builtin_amdgcn_mfma_f32_16x16x32_bf16(kf, qf[ks], St[n], 0, 0, 0);
            }
        }
        __builtin_amdgcn_s_setprio(0);

        float mx = -1e30f;
#pragma unroll
        for (int n = 0; n < 4; n++)
#pragma unroll
            for (int r = 0; r < 4; r++) mx = fmaxf(mx, St[n][r]);
        mx *= scale;
        mx = fmaxf(mx, __shfl_xor(mx, 16));
        mx = fmaxf(mx, __shfl_xor(mx, 32));
        float mn = fmaxf(m_r, mx);
        float alpha = __expf(m_r - mn);
        m_r = mn;
        float p[4][4];
        float rs = 0.f;
#pragma unroll
        for (int n = 0; n < 4; n++)
#pragma unroll
            for (int r = 0; r < 4; r++) {
                float pv = __expf(St[n][r] * scale - mn);
                p[n][r] = pv;
                rs += pv;
            }
        rs += __shfl_xor(rs, 16);
        rs += __shfl_xor(rs, 32);
        l_r = l_r * alpha + rs;

        unsigned P01[4], P23[4];
#pragma unroll
        for (int n = 0; n < 4; n++) {
            P01[n] = (unsigned)f2bf(p[n][0]) | ((unsigned)f2bf(p[n][1]) << 16);
            P23[n] = (unsigned)f2bf(p[n][2]) | ((unsigned)f2bf(p[n][3]) << 16);
        }

#pragma unroll
        for (int r = 0; r < 4; r++) {
            float ar = __shfl(alpha, (lane & 48) + g * 4 + r);
#pragma unroll
            for (int n2 = 0; n2 < 8; n2++) Oa[n2][r] *= ar;
        }

#pragma unroll
        for (int ks2 = 0; ks2 < 2; ks2++) {
            int e = ks2 * 2, od = ks2 * 2 + 1;
            unsigned s16a = (g < 2) ? P01[e] : P01[od];
            unsigned s16b = (g < 2) ? P23[e] : P23[od];
            unsigned s32a = (g & 1) ? P01[e] : P01[od];
            unsigned s32b = (g & 1) ? P23[e] : P23[od];
            unsigned s48a = (g >= 2) ? P01[e] : P01[od];
            unsigned s48b = (g >= 2) ? P23[e] : P23[od];
            unsigned r16a = __shfl_xor(s16a, 16), r16b = __shfl_xor(s16b, 16);
            unsigned r32a = __shfl_xor(s32a, 32), r32b = __shfl_xor(s32b, 32);
            unsigned r48a = __shfl_xor(s48a, 48), r48b = __shfl_xor(s48b, 48);
            union { unsigned u[4]; bf16x8 v; } pa;
            pa.u[0] = (g == 0) ? P01[e] : (g == 1) ? r48a : (g == 2) ? r32a : r16a;
            pa.u[1] = (g == 0) ? P23[e] : (g == 1) ? r48b : (g == 2) ? r32b : r16b;
            pa.u[2] = (g == 0) ? r16a : (g == 1) ? r32a : (g == 2) ? r48a : P01[od];
            pa.u[3] = (g == 0) ? r16b : (g == 1) ? r32b : (g == 2) ? r48b : P23[od];
            __builtin_amdgcn_s_setprio(1);
#pragma unroll
            for (int n2 = 0; n2 < 8; n2++) {
                bf16x8 vf = *(const bf16x8*)&Vc[(n2 * 16 + t) * 64 + (((ks2 * 64 + g * 16) ^ swzt) >> 1)];
                Oa[n2] = __builtin_amdgcn_mfma_f32_16x16x32_bf16(pa.v, vf, Oa[n2], 0, 0, 0);
            }
            __builtin_amdgcn_s_setprio(0);
        }

        if (more) {
            vmwait0();
            barrier_raw();
        }
    }

#pragma unroll
    for (int r = 0; r < 4; r++) {
        float lq = __shfl(l_r, (lane & 48) + g * 4 + r);
        float inv = 1.f / lq;
        int orow = q0 + w * 16 + g * 4 + r;
#pragma unroll
        for (int n2 = 0; n2 < 8; n2++)
            o[(size_t)(b * 1024 + orow) * 1024 + h * 128 + n2 * 16 + t] = f2bf(Oa[n2][r] * inv);
    }
}

extern "C" void kernel_launch(void* const* d_in, const int* in_sizes, int n_in,
                              void* d_out, int out_size, void* d_ws, size_t ws_size,
                              hipStream_t stream) {
    const float* x          = (const float*)d_in[0];
    const float* c          = (const float*)d_in[1];
    const float* m_ada_w    = (const float*)d_in[2];
    const float* m_ada_b    = (const float*)d_in[3];
    const float* m_norm_g   = (const float*)d_in[4];
    const float* m_norm_b   = (const float*)d_in[5];
    const float* in_proj_w  = (const float*)d_in[6];
    const float* in_proj_b  = (const float*)d_in[7];
    const float* out_proj_w = (const float*)d_in[8];
    const float* out_proj_b = (const float*)d_in[9];
    const float* f_ada_w    = (const float*)d_in[10];
    const float* f_ada_b    = (const float*)d_in[11];
    const float* f_norm_g   = (const float*)d_in[12];
    const float* f_norm_b   = (const float*)d_in[13];
    const float* w1         = (const float*)d_in[14];
    const float* b1         = (const float*)d_in[15];
    const float* w2         = (const float*)d_in[16];
    const float* b2         = (const float*)d_in[17];
    float* out = (float*)d_out;
    char* ws = (char*)d_ws;

    unsigned short* Wq   = (unsigned short*)(ws + 0);          // 3072x1024 bf16
    unsigned short* Wo   = (unsigned short*)(ws + 6291456);    // 1024x1024
    unsigned short* vt   = (unsigned short*)(ws + 8388608);    // 64x128x1024 (later W1t/W2t)
    unsigned short* W1t  = (unsigned short*)(ws + 8388608);    // 4096x1024
    unsigned short* W2t  = (unsigned short*)(ws + 16777216);   // 1024x4096
    float*          modm = (float*)(ws + 25165824);            // 8x3072
    float*          modf = (float*)(ws + 25264128);            // 8x3072
    unsigned short* hbuf = (unsigned short*)(ws + 25362432);   // 8192x1024
    float*          part = (float*)(ws + 25362432);            // ada partials (hbuf region)
    float*          part2= (float*)(ws + 25362432 + 2097152);
    unsigned short* qkv  = (unsigned short*)(ws + 42139648);   // 8192x3072
    unsigned short* obuf = (unsigned short*)(ws + 92471296);   // 8192x1024
    unsigned short* h2   = (unsigned short*)(ws + 42139648);   // 8192x4096 (aliases qkv+obuf)

    hipFuncSetAttribute((const void*)&gemmw<0>, hipFuncAttributeMaxDynamicSharedMemorySize, 73728);
    hipFuncSetAttribute((const void*)&gemmw<2>, hipFuncAttributeMaxDynamicSharedMemorySize, 73728);
    hipFuncSetAttribute((const void*)&gemmo<1>, hipFuncAttributeMaxDynamicSharedMemorySize, 49152);
    hipFuncSetAttribute((const void*)&gemmo<3>, hipFuncAttributeMaxDynamicSharedMemorySize, 49152);
    hipFuncSetAttribute((const void*)&attn_kernel, hipFuncAttributeMaxDynamicSharedMemorySize, 65536);

    hipLaunchKernelGGL(ada_mod_part, dim3(12, 16), dim3(256), 0, stream, c, m_ada_w, part);
    hipLaunchKernelGGL(ada_mod_part, dim3(12, 16), dim3(256), 0, stream, c, f_ada_w, part2);
    hipLaunchKernelGGL(ada_reduce, dim3(96), dim3(256), 0, stream, part, m_ada_b, modm);
    hipLaunchKernelGGL(ada_reduce, dim3(96), dim3(256), 0, stream, part2, f_ada_b, modf);

    hipLaunchKernelGGL(f2b4, dim3(3072), dim3(256), 0, stream, in_proj_w, Wq);
    hipLaunchKernelGGL(f2b4, dim3(1024), dim3(256), 0, stream, out_proj_w, Wo);

    hipLaunchKernelGGL(ln_mod_kernel, dim3(8192), dim3(256), 0, stream, x, m_norm_g, m_norm_b, modm, hbuf);
    // qkv: 64 row-panels x 12 cols = 768 blocks; V cols write vt directly
    hipLaunchKernelGGL(HIP_KERNEL_NAME(gemmw<0>), dim3(768), dim3(256), 73728, stream,
                       hbuf, Wq, 3072, 1024, 12, in_proj_b, qkv, vt);
    hipLaunchKernelGGL(attn_kernel, dim3(512), dim3(512), 65536, stream, qkv, vt, obuf);
    // out-proj: 64 x 8 = 512 blocks
    hipLaunchKernelGGL(HIP_KERNEL_NAME(gemmo<1>), dim3(512), dim3(256), 49152, stream,
                       obuf, Wo, 1024, 1024, 8, out_proj_b, x, modm, out);

    hipLaunchKernelGGL(transpose_f2b, dim3(128, 32), dim3(256), 0, stream, w1, W1t, 1024, 4096);
    hipLaunchKernelGGL(transpose_f2b, dim3(32, 128), dim3(256), 0, stream, w2, W2t, 4096, 1024);

    hipLaunchKernelGGL(ln_mod_kernel, dim3(8192), dim3(256), 0, stream, out, f_norm_g, f_norm_b, modf, hbuf);
    // FF1: 64 x 16 = 1024 blocks
    hipLaunchKernelGGL(HIP_KERNEL_NAME(gemmw<2>), dim3(1024), dim3(256), 73728, stream,
                       hbuf, W1t, 4096, 1024, 16, b1, h2, (unsigned short*)nullptr);
    // FF2: K=4096, 64 x 8 = 512 blocks
    hipLaunchKernelGGL(HIP_KERNEL_NAME(gemmo<3>), dim3(512), dim3(256), 49152, stream,
                       h2, W2t, 1024, 4096, 8, b2, (const float*)nullptr, modf, out);
}

// Round 11
// 382.323 us; speedup vs baseline: 1.0309x; 1.0112x over previous
//
#include <hip/hip_runtime.h>

typedef __bf16 bf16x8 __attribute__((ext_vector_type(8)));
typedef float f32x4 __attribute__((ext_vector_type(4)));

__device__ __forceinline__ unsigned short f2bf(float f) {
    unsigned int u = __float_as_uint(f);
    unsigned int r = (u + 0x7FFFu + ((u >> 16) & 1u)) >> 16;
    return (unsigned short)r;
}

__device__ __forceinline__ void gload16(const void* g, void* l) {
    __builtin_amdgcn_global_load_lds(
        (const __attribute__((address_space(1))) unsigned int*)g,
        (__attribute__((address_space(3))) unsigned int*)l, 16, 0, 0);
}

__device__ __forceinline__ void barrier_raw() {
    asm volatile("" ::: "memory");
    __builtin_amdgcn_s_barrier();
    asm volatile("" ::: "memory");
}

__device__ __forceinline__ void vmwait0() {
    asm volatile("s_waitcnt vmcnt(0)" ::: "memory");
}

__device__ __forceinline__ void lgkm0_fence() {
    asm volatile("s_waitcnt lgkmcnt(0)" ::: "memory");
    __builtin_amdgcn_sched_barrier(0);
}

__device__ __forceinline__ float gelu_fast(float u) {
    float z = 1.595769122f * u + 0.071354816f * u * u * u;
    return u / (1.f + __expf(-z));
}

// ---------------- weight convert: fp32 -> bf16, 4 elems/thread ----------------
__global__ __launch_bounds__(256) void f2b4(const float* __restrict__ in,
                                            unsigned short* __restrict__ out) {
    size_t i = ((size_t)blockIdx.x * 256 + threadIdx.x) * 4;
    float4 v = *(const float4*)(in + i);
    ushort4 o;
    o.x = f2bf(v.x); o.y = f2bf(v.y); o.z = f2bf(v.z); o.w = f2bf(v.w);
    *(ushort4*)(out + i) = o;
}

// ------------- transpose + convert: fp32 [R][C] -> bf16 [C][R] ---------------
__global__ __launch_bounds__(256) void transpose_f2b(const float* __restrict__ in,
                                                     unsigned short* __restrict__ out,
                                                     int R, int C) {
    __shared__ float tile[32][33];
    int r0 = blockIdx.y * 32, c0 = blockIdx.x * 32;
    int tx = threadIdx.x & 31, ty = threadIdx.x >> 5;
#pragma unroll
    for (int i = 0; i < 4; i++) {
        int r = ty + i * 8;
        tile[r][tx] = in[(size_t)(r0 + r) * C + c0 + tx];
    }
    __syncthreads();
#pragma unroll
    for (int i = 0; i < 4; i++) {
        int r = ty + i * 8;
        out[(size_t)(c0 + r) * R + r0 + tx] = f2bf(tile[tx][r]);
    }
}

// -------- ada modulation, split-K --------
__global__ __launch_bounds__(256) void ada_mod_part(const float* __restrict__ c,
                                                    const float* __restrict__ W,
                                                    float* __restrict__ partial) {
    __shared__ float sc[8 * 64];
    int kc = blockIdx.y * 64;
    for (int i = threadIdx.x; i < 512; i += 256) {
        int b = i >> 6, k = i & 63;
        float cv = c[b * 1024 + kc + k];
        sc[i] = cv / (1.f + __expf(-cv));
    }
    __syncthreads();
    int j = blockIdx.x * 256 + threadIdx.x;
    float acc[8] = {0, 0, 0, 0, 0, 0, 0, 0};
    for (int k = 0; k < 64; k++) {
        float w = W[(size_t)(kc + k) * 3072 + j];
#pragma unroll
        for (int b = 0; b < 8; b++) acc[b] += sc[b * 64 + k] * w;
    }
#pragma unroll
    for (int b = 0; b < 8; b++) partial[((size_t)blockIdx.y * 8 + b) * 3072 + j] = acc[b];
}

__global__ __launch_bounds__(256) void ada_reduce(const float* __restrict__ partial,
                                                  const float* __restrict__ bias,
                                                  float* __restrict__ out) {
    int idx = blockIdx.x * 256 + threadIdx.x;
    int b = idx / 3072;
    int jj = idx - b * 3072;
    float s = bias[jj];
#pragma unroll
    for (int ch = 0; ch < 16; ch++) s += partial[((size_t)ch * 8 + b) * 3072 + jj];
    out[idx] = s;
}

// -------- LN + adaLN modulate: fp32 row -> bf16 row --------
__global__ __launch_bounds__(256) void ln_mod_kernel(const float* __restrict__ x,
                                                     const float* __restrict__ gamma,
                                                     const float* __restrict__ beta,
                                                     const float* __restrict__ mods,
                                                     unsigned short* __restrict__ out) {
    int row = blockIdx.x;
    int b = row >> 10;
    float4 v = ((const float4*)(x + (size_t)row * 1024))[threadIdx.x];
    float s = v.x + v.y + v.z + v.w;
    float s2 = v.x * v.x + v.y * v.y + v.z * v.z + v.w * v.w;
#pragma unroll
    for (int d = 1; d < 64; d <<= 1) { s += __shfl_xor(s, d); s2 += __shfl_xor(s2, d); }
    __shared__ float red[8];
    int lane = threadIdx.x & 63, wid = threadIdx.x >> 6;
    if (lane == 0) { red[wid] = s; red[4 + wid] = s2; }
    __syncthreads();
    float S = red[0] + red[1] + red[2] + red[3];
    float S2 = red[4] + red[5] + red[6] + red[7];
    float mu = S * (1.f / 1024.f);
    float var = S2 * (1.f / 1024.f) - mu * mu;
    float rs = rsqrtf(var + 1e-6f);
    const float* mrow = mods + b * 3072;
    int j0 = threadIdx.x * 4;
    float hv[4] = {v.x, v.y, v.z, v.w};
    ushort4 o;
    unsigned short* op = (unsigned short*)&o;
#pragma unroll
    for (int i = 0; i < 4; i++) {
        int j = j0 + i;
        float hh = (hv[i] - mu) * rs * gamma[j] + beta[j];
        hh = hh * (1.f + mrow[1024 + j]) + mrow[j];
        op[i] = f2bf(hh);
    }
    *(ushort4*)(out + (size_t)row * 1024 + j0) = o;
}

// ============ m201-faithful 8-phase GEMM: BM=BN=256, BK=64, 512 thr ============
// 8 waves 2x4, per-wave 128x64.  LDS 128KB: 2dbuf x (A 256x64 + B 256x64).
// Per K-tile: 4 phases = quadrants (0,0),(1,0),(1,1),(0,1); per phase read only
// the CHANGED operand half (a0+b0=12 / a1=8 / b1=4 / none), stage 1-2 halves,
// 2 barriers around {lgkmcnt(0); setprio; 16 MFMA}.  Stage plan: ph1 B1(t+1),
// ph3 A0(t+2), ph4 A1+B0(t+2); ONE vmcnt(6) per tile (verified accounting:
// completes exactly tile t+1's 4 halves, leaves t+2's 3 in flight).
// Swizzle: 8x16B slots per 128B row, slot ^= (row&7); source pre-swizzled.
// EP: 0 = +bias -> bf16 (cols>=2048 write V^T to vt), 2 = gelu(acc+bias) -> bf16
template <int EP>
__global__ __launch_bounds__(512, 2) void gemm8(const unsigned short* __restrict__ A,
                                                const unsigned short* __restrict__ Bt,
                                                int N, int K, int nx,
                                                const float* __restrict__ bias,
                                                unsigned short* __restrict__ outb,
                                                unsigned short* __restrict__ vt) {
    constexpr int TE = 256 * 64;            // elems per tile buffer per operand
    extern __shared__ __align__(16) char smem[];
    __bf16* As = (__bf16*)smem;             // 2 x TE
    __bf16* Bs = As + 2 * TE;               // 2 x TE

    int tid = threadIdx.x, lane = tid & 63, wid = tid >> 6;
    int wr = wid >> 2, wc = wid & 3;
    int t = lane & 15, g = lane >> 4;
    int xk = (t & 7) * 8;                   // fragment-read slot XOR (elems)

    int nwg = gridDim.x, chunk = nwg >> 3;
    int swz = (blockIdx.x & 7) * chunk + (blockIdx.x >> 3);
    int bx = swz % nx, by = swz / nx;
    int rowA0 = by * 256, colB0 = bx * 256;

    int rin = tid >> 3, cblk = tid & 7;     // rin 0..63, 8x16B chunks per row
    int scol = (cblk ^ (rin & 7)) * 8;      // pre-swizzled source col (elems)

    auto stageA = [&](int d, int h, int kt) {   // half h = rows h*128..+127, 2 loads
        int k0 = kt << 6;
        const unsigned short* src = A + (size_t)(rowA0 + h * 128 + rin) * K + k0 + scol;
        __bf16* dst = As + d * TE + (h * 128 + rin) * 64 + cblk * 8;
        gload16(src, dst);
        gload16(src + (size_t)64 * K, dst + 4096);
    };
    auto stageB = [&](int d, int h, int kt) {
        int k0 = kt << 6;
        const unsigned short* src = Bt + (size_t)(colB0 + h * 128 + rin) * K + k0 + scol;
        __bf16* dst = Bs + d * TE + (h * 128 + rin) * 64 + cblk * 8;
        gload16(src, dst);
        gload16(src + (size_t)64 * K, dst + 4096);
    };

    f32x4 acc[8][4];
#pragma unroll
    for (int m = 0; m < 8; m++)
#pragma unroll
        for (int n = 0; n < 4; n++) acc[m][n] = (f32x4){0.f, 0.f, 0.f, 0.f};

    int NT = K >> 6;
    // prologue: tile0 complete + tile1 {A0,A1,B0}; vmcnt(6) -> tile0 ready
    stageA(0, 0, 0); stageA(0, 1, 0); stageB(0, 0, 0); stageB(0, 1, 0);
    if (NT > 1) {
        stageA(1, 0, 1); stageA(1, 1, 1); stageB(1, 0, 1);
        asm volatile("s_waitcnt vmcnt(6)" ::: "memory");
    } else {
        vmwait0();
    }
    barrier_raw();

#pragma unroll 1
    for (int kt = 0; kt < NT; ++kt) {
        int d = kt & 1, dn = d ^ 1;
        const __bf16* Ab = As + d * TE;
        const __bf16* Bb = Bs + d * TE;
        bool s1 = kt + 1 < NT, s2 = kt + 2 < NT;

        auto LDA = [&](int mh, int m4, int ks) -> bf16x8 {
            int R = wr * 128 + mh * 64 + m4 * 16 + t;
            return *(const bf16x8*)&Ab[R * 64 + ((ks * 32 + g * 8) ^ xk)];
        };
        auto LDB = [&](int nh, int n2, int ks) -> bf16x8 {
            int R = wc * 64 + nh * 32 + n2 * 16 + t;
            return *(const bf16x8*)&Bb[R * 64 + ((ks * 32 + g * 8) ^ xk)];
        };

        bf16x8 a0[4][2], a1[4][2], b0[2][2], b1[2][2];

        // ---- phase 1: quadrant (mh0,nh0); read a0+b0; stage B1(t+1) ----
#pragma unroll
        for (int m4 = 0; m4 < 4; m4++) { a0[m4][0] = LDA(0, m4, 0); a0[m4][1] = LDA(0, m4, 1); }
#pragma unroll
        for (int n2 = 0; n2 < 2; n2++) { b0[n2][0] = LDB(0, n2, 0); b0[n2][1] = LDB(0, n2, 1); }
        if (s1) stageB(dn, 1, kt + 1);
        barrier_raw();
        lgkm0_fence();
        __builtin_amdgcn_s_setprio(1);
#pragma unroll
        for (int m4 = 0; m4 < 4; m4++)
#pragma unroll
            for (int n2 = 0; n2 < 2; n2++)
#pragma unroll
                for (int ks = 0; ks < 2; ks++)
                    acc[m4][n2] = __builtin_amdgcn_mfma_f32_16x16x32_bf16(a0[m4][ks], b0[n2][ks], acc[m4][n2], 0, 0, 0);
        __builtin_amdgcn_s_setprio(0);
        barrier_raw();

        // ---- phase 2: quadrant (mh1,nh0); read a1 ----
#pragma unroll
        for (int m4 = 0; m4 < 4; m4++) { a1[m4][0] = LDA(1, m4, 0); a1[m4][1] = LDA(1, m4, 1); }
        barrier_raw();
        lgkm0_fence();
        __builtin_amdgcn_s_setprio(1);
#pragma unroll
        for (int m4 = 0; m4 < 4; m4++)
#pragma unroll
            for (int n2 = 0; n2 < 2; n2++)
#pragma unroll
                for (int ks = 0; ks < 2; ks++)
                    acc[4 + m4][n2] = __builtin_amdgcn_mfma_f32_16x16x32_bf16(a1[m4][ks], b0[n2][ks], acc[4 + m4][n2], 0, 0, 0);
        __builtin_amdgcn_s_setprio(0);
        barrier_raw();

        // ---- phase 3: quadrant (mh1,nh1); read b1; stage A0(t+2) ----
#pragma unroll
        for (int n2 = 0; n2 < 2; n2++) { b1[n2][0] = LDB(1, n2, 0); b1[n2][1] = LDB(1, n2, 1); }
        if (s2) stageA(d, 0, kt + 2);
        barrier_raw();
        lgkm0_fence();
        __builtin_amdgcn_s_setprio(1);
#pragma unroll
        for (int m4 = 0; m4 < 4; m4++)
#pragma unroll
            for (int n2 = 0; n2 < 2; n2++)
#pragma unroll
                for (int ks = 0; ks < 2; ks++)
                    acc[4 + m4][2 + n2] = __builtin_amdgcn_mfma_f32_16x16x32_bf16(a1[m4][ks], b1[n2][ks], acc[4 + m4][2 + n2], 0, 0, 0);
        __builtin_amdgcn_s_setprio(0);
        barrier_raw();

        // ---- phase 4: quadrant (mh0,nh1); a0 kept in regs; stage A1+B0(t+2) ----
        if (s2) { stageA(d, 1, kt + 2); stageB(d, 0, kt + 2); }
        __builtin_amdgcn_s_setprio(1);
#pragma unroll
        for (int m4 = 0; m4 < 4; m4++)
#pragma unroll
            for (int n2 = 0; n2 < 2; n2++)
#pragma unroll
                for (int ks = 0; ks < 2; ks++)
                    acc[m4][2 + n2] = __builtin_amdgcn_mfma_f32_16x16x32_bf16(a0[m4][ks], b1[n2][ks], acc[m4][2 + n2], 0, 0, 0);
        __builtin_amdgcn_s_setprio(0);
        if (s1) {
            if (s2) {
                asm volatile("s_waitcnt vmcnt(6)" ::: "memory");
            } else {
                asm volatile("s_waitcnt vmcnt(0)" ::: "memory");
            }
            barrier_raw();
        }
    }

    // ---- epilogue ----
    int col0 = colB0 + wc * 64;
    bool vpart = (EP == 0) && (colB0 >= 2048);
#pragma unroll
    for (int m = 0; m < 8; m++)
#pragma unroll
        for (int n = 0; n < 4; n++) {
            int col = col0 + n * 16 + t;
            if (EP == 0 && vpart) {
                int hcol = col - 2048;
                int hh = hcol >> 7, dd = hcol & 127;
                int row0 = rowA0 + wr * 128 + m * 16 + g * 4;
                int bb = row0 >> 10;
                int ntok = row0 & 1023;
                float bs = bias[col];
                ushort4 vv;
                vv.x = f2bf(acc[m][n][0] + bs);
                vv.y = f2bf(acc[m][n][1] + bs);
                vv.z = f2bf(acc[m][n][2] + bs);
                vv.w = f2bf(acc[m][n][3] + bs);
                *(ushort4*)(vt + (((size_t)(bb * 8 + hh) * 128 + dd) * 1024 + ntok)) = vv;
            } else {
#pragma unroll
                for (int r = 0; r < 4; r++) {
                    int row = rowA0 + wr * 128 + m * 16 + g * 4 + r;
                    float v = acc[m][n][r];
                    if (EP == 0) {
                        outb[(size_t)row * N + col] = f2bf(v + bias[col]);
                    } else {
                        outb[(size_t)row * N + col] = f2bf(gelu_fast(v + bias[col]));
                    }
                }
            }
        }
}

// ============ depth-2 prefetch GEMM (NF2): BM=128, BN=128, BK=32 ============
// 256 thr (4 waves 2x2), per-wave 64x64, LDS = 3 x 16KB = 48KB (3 blocks/CU).
// EP: 1 = x+gate*(acc+bias) -> f32, 3 = outf += gate*(acc+bias)
template <int EP>
__global__ __launch_bounds__(256, 4) void gemmo(const unsigned short* __restrict__ A,
                                                const unsigned short* __restrict__ Bt,
                                                int N, int K, int nx,
                                                const float* __restrict__ bias,
                                                const float* __restrict__ xres,
                                                const float* __restrict__ mods,
                                                float* __restrict__ outf) {
    constexpr int AE = 128 * 32;
    constexpr int BE = 128 * 32;
    extern __shared__ __align__(16) char smem[];
    __bf16* As = (__bf16*)smem;             // 3 x AE
    __bf16* Bs = As + 3 * AE;               // 3 x BE

    int tid = threadIdx.x, lane = tid & 63, wid = tid >> 6;
    int wr = wid >> 1, wc = wid & 1;
    int t = lane & 15, g = lane >> 4;
    int xk2 = ((t >> 1) & 3) * 8;

    int nwg = gridDim.x, chunk = nwg >> 3;
    int swz = (blockIdx.x & 7) * chunk + (blockIdx.x >> 3);
    int bx = swz % nx, by = swz / nx;
    int rowA0 = by * 128, colB0 = bx * 128;

    int rin = tid >> 2, cblk = tid & 3;
    int scol = (cblk ^ ((rin >> 1) & 3)) * 8;

    auto stage = [&](int nb, int kt) {          // 4 gload16
        int k0 = kt << 5;
        gload16(A + (size_t)(rowA0 + rin) * K + k0 + scol, As + nb * AE + tid * 8);
        gload16(A + (size_t)(rowA0 + 64 + rin) * K + k0 + scol,
                As + nb * AE + 2048 + tid * 8);
        gload16(Bt + (size_t)(colB0 + rin) * K + k0 + scol, Bs + nb * BE + tid * 8);
        gload16(Bt + (size_t)(colB0 + 64 + rin) * K + k0 + scol,
                Bs + nb * BE + 2048 + tid * 8);
    };

    f32x4 acc[4][4];
#pragma unroll
    for (int m = 0; m < 4; m++)
#pragma unroll
        for (int n = 0; n < 4; n++) acc[m][n] = (f32x4){0.f, 0.f, 0.f, 0.f};

    int NT = K >> 5;
    stage(0, 0);
    if (NT > 1) {
        stage(1, 1);
        asm volatile("s_waitcnt vmcnt(4)" ::: "memory");
    } else {
        vmwait0();
    }
    barrier_raw();

    int cur = 0, tgt = 2;
#pragma unroll 1
    for (int kt = 0; kt < NT; ++kt) {
        bool deep = (kt + 2) < NT;
        bool more = (kt + 1) < NT;
        if (deep) stage(tgt, kt + 2);
        const __bf16* Ac = As + cur * AE;
        const __bf16* Bc = Bs + cur * BE;

        bf16x8 a[4], b[4];
#pragma unroll
        for (int m = 0; m < 4; m++)
            a[m] = *(const bf16x8*)&Ac[(wr * 64 + m * 16 + t) * 32 + ((g * 8) ^ xk2)];
#pragma unroll
        for (int n = 0; n < 4; n++)
            b[n] = *(const bf16x8*)&Bc[(wc * 64 + n * 16 + t) * 32 + ((g * 8) ^ xk2)];

        __builtin_amdgcn_s_setprio(1);
#pragma unroll
        for (int m = 0; m < 4; m++)
#pragma unroll
            for (int n = 0; n < 4; n++)
                acc[m][n] = __builtin_amdgcn_mfma_f32_16x16x32_bf16(a[m], b[n], acc[m][n], 0, 0, 0);
        __builtin_amdgcn_s_setprio(0);

        if (more) {
            if (deep) {
                asm volatile("s_waitcnt vmcnt(4)" ::: "memory");
            } else {
                vmwait0();
            }
            barrier_raw();
        }
        cur = (cur == 2) ? 0 : cur + 1;
        tgt = (tgt == 2) ? 0 : tgt + 1;
    }

    int row0 = rowA0 + wr * 64, col0 = colB0 + wc * 64;
#pragma unroll
    for (int m = 0; m < 4; m++)
#pragma unroll
        for (int n = 0; n < 4; n++) {
            int col = col0 + n * 16 + t;
#pragma unroll
            for (int r = 0; r < 4; r++) {
                int row = row0 + m * 16 + g * 4 + r;
                float v = acc[m][n][r];
                int bb = row >> 10;
                float gt = mods[bb * 3072 + 2048 + col];
                if (EP == 1) {
                    outf[(size_t)row * 1024 + col] =
                        xres[(size_t)row * 1024 + col] + gt * (v + bias[col]);
                } else {
                    outf[(size_t)row * 1024 + col] += gt * (v + bias[col]);
                }
            }
        }
}

// ======== flash attention, swapped-QK^T in-register softmax ========
__global__ __launch_bounds__(512, 4) void attn_kernel(const unsigned short* __restrict__ qkv,
                                                      const unsigned short* __restrict__ vt,
                                                      unsigned short* __restrict__ o) {
    extern __shared__ __align__(16) char asmem[];
    __bf16* Ks = (__bf16*)asmem;
    __bf16* Vts = Ks + 2 * 64 * 128;

    int bid = blockIdx.x;
    int logical = (bid & 7) * 64 + (bid >> 3);
    int q0 = (logical & 7) * 128;
    int bh = logical >> 3;
    int b = bh >> 3, h = bh & 7;
    int tid = threadIdx.x, lane = tid & 63, w = tid >> 6;
    int t = lane & 15, g = lane >> 4;
    int swzt = (t & 7) << 4;

    const unsigned short* qbase = qkv + (size_t)(b * 1024) * 3072 + h * 128;
    int qrow = q0 + w * 16 + t;
    bf16x8 qf[4];
#pragma unroll
    for (int ks = 0; ks < 4; ks++)
        qf[ks] = *(const bf16x8*)(qbase + (size_t)qrow * 3072 + ks * 32 + g * 8);

    f32x4 Oa[8];
#pragma unroll
    for (int n = 0; n < 8; n++) Oa[n] = (f32x4){0.f, 0.f, 0.f, 0.f};
    float m_r = -1e30f, l_r = 0.f;
    const float scale = 0.08838834764831845f;

    int krow = tid >> 4;
    int ksrc = (((tid & 15) * 16) ^ ((krow & 7) << 4)) >> 1;
    int vrow = tid >> 3;
    int vsrc = (((tid & 7) * 16) ^ ((vrow & 7) << 4)) >> 1;
    const unsigned short* vtg = vt + (size_t)bh * 128 * 1024;

    auto stage = [&](int buf, int kv0) {
        const unsigned short* kb = qkv + (size_t)(b * 1024 + kv0) * 3072 + 1024 + h * 128;
#pragma unroll
        for (int cc = 0; cc < 2; cc++) {
            gload16(kb + (size_t)(cc * 32 + krow) * 3072 + ksrc,
                    (void*)(Ks + buf * 8192 + cc * 4096 + tid * 8));
            gload16(vtg + (size_t)(cc * 64 + vrow) * 1024 + kv0 + vsrc,
                    (void*)(Vts + buf * 8192 + cc * 4096 + tid * 8));
        }
    };

    stage(0, 0);
    vmwait0();
    barrier_raw();

#pragma unroll 1
    for (int tile = 0; tile < 16; ++tile) {
        int cur = tile & 1;
        bool more = tile < 15;
        if (more) stage(cur ^ 1, (tile + 1) * 64);
        const __bf16* Kc = Ks + cur * 8192;
        const __bf16* Vc = Vts + cur * 8192;

        f32x4 St[4];
#pragma unroll
        for (int n = 0; n < 4; n++) St[n] = (f32x4){0.f, 0.f, 0.f, 0.f};
        __builtin_amdgcn_s_setprio(1);
#pragma unroll
        for (int ks = 0; ks < 4; ks++) {
#pragma unroll
            for (int n = 0; n < 4; n++) {
                bf16x8 kf = *(const bf16x8*)&Kc[(n * 16 + t) * 128 + (((ks * 64 + g * 16) ^ swzt) >> 1)];
                St[n] = __builtin_amdgcn_mfma_f32_16x16x32_bf16(kf, qf[ks], St[n], 0, 0, 0);
            }
        }
        __builtin_amdgcn_s_setprio(0);

        float mx = -1e30f;
#pragma unroll
        for (int n = 0; n < 4; n++)
#pragma unroll
            for (int r = 0; r < 4; r++) mx = fmaxf(mx, St[n][r]);
        mx *= scale;
        mx = fmaxf(mx, __shfl_xor(mx, 16));
        mx = fmaxf(mx, __shfl_xor(mx, 32));
        float mn = fmaxf(m_r, mx);
        float alpha = __expf(m_r - mn);
        m_r = mn;
        float p[4][4];
        float rs = 0.f;
#pragma unroll
        for (int n = 0; n < 4; n++)
#pragma unroll
            for (int r = 0; r < 4; r++) {
                float pv = __expf(St[n][r] * scale - mn);
                p[n][r] = pv;
                rs += pv;
            }
        rs += __shfl_xor(rs, 16);
        rs += __shfl_xor(rs, 32);
        l_r = l_r * alpha + rs;

        unsigned P01[4], P23[4];
#pragma unroll
        for (int n = 0; n < 4; n++) {
            P01[n] = (unsigned)f2bf(p[n][0]) | ((unsigned)f2bf(p[n][1]) << 16);
            P23[n] = (unsigned)f2bf(p[n][2]) | ((unsigned)f2bf(p[n][3]) << 16);
        }

#pragma unroll
        for (int r = 0; r < 4; r++) {
            float ar = __shfl(alpha, (lane & 48) + g * 4 + r);
#pragma unroll
            for (int n2 = 0; n2 < 8; n2++) Oa[n2][r] *= ar;
        }

#pragma unroll
        for (int ks2 = 0; ks2 < 2; ks2++) {
            int e = ks2 * 2, od = ks2 * 2 + 1;
            unsigned s16a = (g < 2) ? P01[e] : P01[od];
            unsigned s16b = (g < 2) ? P23[e] : P23[od];
            unsigned s32a = (g & 1) ? P01[e] : P01[od];
            unsigned s32b = (g & 1) ? P23[e] : P23[od];
            unsigned s48a = (g >= 2) ? P01[e] : P01[od];
            unsigned s48b = (g >= 2) ? P23[e] : P23[od];
            unsigned r16a = __shfl_xor(s16a, 16), r16b = __shfl_xor(s16b, 16);
            unsigned r32a = __shfl_xor(s32a, 32), r32b = __shfl_xor(s32b, 32);
            unsigned r48a = __shfl_xor(s48a, 48), r48b = __shfl_xor(s48b, 48);
            union { unsigned u[4]; bf16x8 v; } pa;
            pa.u[0] = (g == 0) ? P01[e] : (g == 1) ? r48a : (g == 2) ? r32a : r16a;
            pa.u[1] = (g == 0) ? P23[e] : (g == 1) ? r48b : (g == 2) ? r32b : r16b;
            pa.u[2] = (g == 0) ? r16a : (g == 1) ? r32a : (g == 2) ? r48a : P01[od];
            pa.u[3] = (g == 0) ? r16b : (g == 1) ? r32b : (g == 2) ? r48b : P23[od];
            __builtin_amdgcn_s_setprio(1);
#pragma unroll
            for (int n2 = 0; n2 < 8; n2++) {
                bf16x8 vf = *(const bf16x8*)&Vc[(n2 * 16 + t) * 64 + (((ks2 * 64 + g * 16) ^ swzt) >> 1)];
                Oa[n2] = __builtin_amdgcn_mfma_f32_16x16x32_bf16(pa.v, vf, Oa[n2], 0, 0, 0);
            }
            __builtin_amdgcn_s_setprio(0);
        }

        if (more) {
            vmwait0();
            barrier_raw();
        }
    }

#pragma unroll
    for (int r = 0; r < 4; r++) {
        float lq = __shfl(l_r, (lane & 48) + g * 4 + r);
        float inv = 1.f / lq;
        int orow = q0 + w * 16 + g * 4 + r;
#pragma unroll
        for (int n2 = 0; n2 < 8; n2++)
            o[(size_t)(b * 1024 + orow) * 1024 + h * 128 + n2 * 16 + t] = f2bf(Oa[n2][r] * inv);
    }
}

extern "C" void kernel_launch(void* const* d_in, const int* in_sizes, int n_in,
                              void* d_out, int out_size, void* d_ws, size_t ws_size,
                              hipStream_t stream) {
    const float* x          = (const float*)d_in[0];
    const float* c          = (const float*)d_in[1];
    const float* m_ada_w    = (const float*)d_in[2];
    const float* m_ada_b    = (const float*)d_in[3];
    const float* m_norm_g   = (const float*)d_in[4];
    const float* m_norm_b   = (const float*)d_in[5];
    const float* in_proj_w  = (const float*)d_in[6];
    const float* in_proj_b  = (const float*)d_in[7];
    const float* out_proj_w = (const float*)d_in[8];
    const float* out_proj_b = (const float*)d_in[9];
    const float* f_ada_w    = (const float*)d_in[10];
    const float* f_ada_b    = (const float*)d_in[11];
    const float* f_norm_g   = (const float*)d_in[12];
    const float* f_norm_b   = (const float*)d_in[13];
    const float* w1         = (const float*)d_in[14];
    const float* b1         = (const float*)d_in[15];
    const float* w2         = (const float*)d_in[16];
    const float* b2         = (const float*)d_in[17];
    float* out = (float*)d_out;
    char* ws = (char*)d_ws;

    unsigned short* Wq   = (unsigned short*)(ws + 0);          // 3072x1024 bf16
    unsigned short* Wo   = (unsigned short*)(ws + 6291456);    // 1024x1024
    unsigned short* vt   = (unsigned short*)(ws + 8388608);    // 64x128x1024 (later W1t/W2t)
    unsigned short* W1t  = (unsigned short*)(ws + 8388608);    // 4096x1024
    unsigned short* W2t  = (unsigned short*)(ws + 16777216);   // 1024x4096
    float*          modm = (float*)(ws + 25165824);            // 8x3072
    float*          modf = (float*)(ws + 25264128);            // 8x3072
    unsigned short* hbuf = (unsigned short*)(ws + 25362432);   // 8192x1024
    float*          part = (float*)(ws + 25362432);            // ada partials (hbuf region)
    float*          part2= (float*)(ws + 25362432 + 2097152);
    unsigned short* qkv  = (unsigned short*)(ws + 42139648);   // 8192x3072
    unsigned short* obuf = (unsigned short*)(ws + 92471296);   // 8192x1024
    unsigned short* h2   = (unsigned short*)(ws + 42139648);   // 8192x4096 (aliases qkv+obuf)

    hipFuncSetAttribute((const void*)&gemm8<0>, hipFuncAttributeMaxDynamicSharedMemorySize, 131072);
    hipFuncSetAttribute((const void*)&gemm8<2>, hipFuncAttributeMaxDynamicSharedMemorySize, 131072);
    hipFuncSetAttribute((const void*)&gemmo<1>, hipFuncAttributeMaxDynamicSharedMemorySize, 49152);
    hipFuncSetAttribute((const void*)&gemmo<3>, hipFuncAttributeMaxDynamicSharedMemorySize, 49152);
    hipFuncSetAttribute((const void*)&attn_kernel, hipFuncAttributeMaxDynamicSharedMemorySize, 65536);

    hipLaunchKernelGGL(ada_mod_part, dim3(12, 16), dim3(256), 0, stream, c, m_ada_w, part);
    hipLaunchKernelGGL(ada_mod_part, dim3(12, 16), dim3(256), 0, stream, c, f_ada_w, part2);
    hipLaunchKernelGGL(ada_reduce, dim3(96), dim3(256), 0, stream, part, m_ada_b, modm);
    hipLaunchKernelGGL(ada_reduce, dim3(96), dim3(256), 0, stream, part2, f_ada_b, modf);

    hipLaunchKernelGGL(f2b4, dim3(3072), dim3(256), 0, stream, in_proj_w, Wq);
    hipLaunchKernelGGL(f2b4, dim3(1024), dim3(256), 0, stream, out_proj_w, Wo);

    hipLaunchKernelGGL(ln_mod_kernel, dim3(8192), dim3(256), 0, stream, x, m_norm_g, m_norm_b, modm, hbuf);
    // qkv: 32 row-panels x 12 cols = 384 blocks; V cols write vt directly
    hipLaunchKernelGGL(HIP_KERNEL_NAME(gemm8<0>), dim3(384), dim3(512), 131072, stream,
                       hbuf, Wq, 3072, 1024, 12, in_proj_b, qkv, vt);
    hipLaunchKernelGGL(attn_kernel, dim3(512), dim3(512), 65536, stream, qkv, vt, obuf);
    // out-proj: 64 x 8 = 512 blocks
    hipLaunchKernelGGL(HIP_KERNEL_NAME(gemmo<1>), dim3(512), dim3(256), 49152, stream,
                       obuf, Wo, 1024, 1024, 8, out_proj_b, x, modm, out);

    hipLaunchKernelGGL(transpose_f2b, dim3(128, 32), dim3(256), 0, stream, w1, W1t, 1024, 4096);
    hipLaunchKernelGGL(transpose_f2b, dim3(32, 128), dim3(256), 0, stream, w2, W2t, 4096, 1024);

    hipLaunchKernelGGL(ln_mod_kernel, dim3(8192), dim3(256), 0, stream, out, f_norm_g, f_norm_b, modf, hbuf);
    // FF1: 32 x 16 = 512 blocks
    hipLaunchKernelGGL(HIP_KERNEL_NAME(gemm8<2>), dim3(512), dim3(512), 131072, stream,
                       hbuf, W1t, 4096, 1024, 16, b1, h2, (unsigned short*)nullptr);
    // FF2: K=4096, 64 x 8 = 512 blocks
    hipLaunchKernelGGL(HIP_KERNEL_NAME(gemmo<3>), dim3(512), dim3(256), 49152, stream,
                       h2, W2t, 1024, 4096, 8, b2, (const float*)nullptr, modf, out);
}

// Round 12
// 377.792 us; speedup vs baseline: 1.0433x; 1.0120x over previous
//
#include <hip/hip_runtime.h>

typedef __bf16 bf16x8 __attribute__((ext_vector_type(8)));
typedef float f32x4 __attribute__((ext_vector_type(4)));

__device__ __forceinline__ unsigned short f2bf(float f) {
    unsigned int u = __float_as_uint(f);
    unsigned int r = (u + 0x7FFFu + ((u >> 16) & 1u)) >> 16;
    return (unsigned short)r;
}

__device__ __forceinline__ void gload16(const void* g, void* l) {
    __builtin_amdgcn_global_load_lds(
        (const __attribute__((address_space(1))) unsigned int*)g,
        (__attribute__((address_space(3))) unsigned int*)l, 16, 0, 0);
}

__device__ __forceinline__ void barrier_raw() {
    asm volatile("" ::: "memory");
    __builtin_amdgcn_s_barrier();
    asm volatile("" ::: "memory");
}

__device__ __forceinline__ void vmwait0() {
    asm volatile("s_waitcnt vmcnt(0)" ::: "memory");
}

__device__ __forceinline__ float gelu_fast(float u) {
    float z = 1.595769122f * u + 0.071354816f * u * u * u;
    return u / (1.f + __expf(-z));
}

// ---------------- weight convert: fp32 -> bf16, 4 elems/thread ----------------
__global__ __launch_bounds__(256) void f2b4(const float* __restrict__ in,
                                            unsigned short* __restrict__ out) {
    size_t i = ((size_t)blockIdx.x * 256 + threadIdx.x) * 4;
    float4 v = *(const float4*)(in + i);
    ushort4 o;
    o.x = f2bf(v.x); o.y = f2bf(v.y); o.z = f2bf(v.z); o.w = f2bf(v.w);
    *(ushort4*)(out + i) = o;
}

// ------------- transpose + convert: fp32 [R][C] -> bf16 [C][R] ---------------
__global__ __launch_bounds__(256) void transpose_f2b(const float* __restrict__ in,
                                                     unsigned short* __restrict__ out,
                                                     int R, int C) {
    __shared__ float tile[32][33];
    int r0 = blockIdx.y * 32, c0 = blockIdx.x * 32;
    int tx = threadIdx.x & 31, ty = threadIdx.x >> 5;
#pragma unroll
    for (int i = 0; i < 4; i++) {
        int r = ty + i * 8;
        tile[r][tx] = in[(size_t)(r0 + r) * C + c0 + tx];
    }
    __syncthreads();
#pragma unroll
    for (int i = 0; i < 4; i++) {
        int r = ty + i * 8;
        out[(size_t)(c0 + r) * R + r0 + tx] = f2bf(tile[tx][r]);
    }
}

// -------- ada modulation, split-K, both branches in one launch (z = m/f) --------
__global__ __launch_bounds__(256) void ada_mod_part(const float* __restrict__ c,
                                                    const float* __restrict__ W0,
                                                    const float* __restrict__ W1,
                                                    float* __restrict__ p0,
                                                    float* __restrict__ p1) {
    const float* W = blockIdx.z ? W1 : W0;
    float* partial = blockIdx.z ? p1 : p0;
    __shared__ float sc[8 * 64];
    int kc = blockIdx.y * 64;
    for (int i = threadIdx.x; i < 512; i += 256) {
        int b = i >> 6, k = i & 63;
        float cv = c[b * 1024 + kc + k];
        sc[i] = cv / (1.f + __expf(-cv));
    }
    __syncthreads();
    int j = blockIdx.x * 256 + threadIdx.x;
    float acc[8] = {0, 0, 0, 0, 0, 0, 0, 0};
    for (int k = 0; k < 64; k++) {
        float w = W[(size_t)(kc + k) * 3072 + j];
#pragma unroll
        for (int b = 0; b < 8; b++) acc[b] += sc[b * 64 + k] * w;
    }
#pragma unroll
    for (int b = 0; b < 8; b++) partial[((size_t)blockIdx.y * 8 + b) * 3072 + j] = acc[b];
}

__global__ __launch_bounds__(256) void ada_reduce(const float* __restrict__ p0,
                                                  const float* __restrict__ p1,
                                                  const float* __restrict__ b0,
                                                  const float* __restrict__ b1,
                                                  float* __restrict__ o0,
                                                  float* __restrict__ o1) {
    const float* partial = blockIdx.y ? p1 : p0;
    const float* bias = blockIdx.y ? b1 : b0;
    float* out = blockIdx.y ? o1 : o0;
    int idx = blockIdx.x * 256 + threadIdx.x;
    int b = idx / 3072;
    int jj = idx - b * 3072;
    float s = bias[jj];
#pragma unroll
    for (int ch = 0; ch < 16; ch++) s += partial[((size_t)ch * 8 + b) * 3072 + jj];
    out[idx] = s;
}

// -------- LN + adaLN modulate: fp32 row -> bf16 row --------
__global__ __launch_bounds__(256) void ln_mod_kernel(const float* __restrict__ x,
                                                     const float* __restrict__ gamma,
                                                     const float* __restrict__ beta,
                                                     const float* __restrict__ mods,
                                                     unsigned short* __restrict__ out) {
    int row = blockIdx.x;
    int b = row >> 10;
    float4 v = ((const float4*)(x + (size_t)row * 1024))[threadIdx.x];
    float s = v.x + v.y + v.z + v.w;
    float s2 = v.x * v.x + v.y * v.y + v.z * v.z + v.w * v.w;
#pragma unroll
    for (int d = 1; d < 64; d <<= 1) { s += __shfl_xor(s, d); s2 += __shfl_xor(s2, d); }
    __shared__ float red[8];
    int lane = threadIdx.x & 63, wid = threadIdx.x >> 6;
    if (lane == 0) { red[wid] = s; red[4 + wid] = s2; }
    __syncthreads();
    float S = red[0] + red[1] + red[2] + red[3];
    float S2 = red[4] + red[5] + red[6] + red[7];
    float mu = S * (1.f / 1024.f);
    float var = S2 * (1.f / 1024.f) - mu * mu;
    float rs = rsqrtf(var + 1e-6f);
    const float* mrow = mods + b * 3072;
    int j0 = threadIdx.x * 4;
    float hv[4] = {v.x, v.y, v.z, v.w};
    ushort4 o;
    unsigned short* op = (unsigned short*)&o;
#pragma unroll
    for (int i = 0; i < 4; i++) {
        int j = j0 + i;
        float hh = (hv[i] - mu) * rs * gamma[j] + beta[j];
        hh = hh * (1.f + mrow[1024 + j]) + mrow[j];
        op[i] = f2bf(hh);
    }
    *(ushort4*)(out + (size_t)row * 1024 + j0) = o;
}

// ============ big-tile multi-block GEMM: BM=BN=256, BK=32, 512 thr ============
// 8 waves 2x4, per-wave 128x64.  LDS = 2dbuf x (A 16KB + B 16KB) = 64KB ->
// 2 independent blocks/CU (cross-block stall cover) WITH the big tile
// (12 b128 reads per 32 MFMA per wave).  Per K-tile: 2 phases {reads+stage ->
// setprio 16 MFMA}; stage A(t+1)@ph1, B(t+1)@ph2; vmcnt(0)+barrier once/tile.
// 64B LDS rows, (row>>1)&3 16B-slot XOR (r8-measured 0 conflicts), source
// pre-swizzled for global_load_lds.
// EP: 0 = +bias -> bf16 (cols>=2048 write V^T to vt), 2 = gelu(acc+bias) -> bf16
template <int EP>
__global__ __launch_bounds__(512, 2) void gemm9(const unsigned short* __restrict__ A,
                                                const unsigned short* __restrict__ Bt,
                                                int N, int K, int nx,
                                                const float* __restrict__ bias,
                                                unsigned short* __restrict__ outb,
                                                unsigned short* __restrict__ vt) {
    constexpr int TE = 256 * 32;            // 8192 elems per operand buffer (16KB)
    extern __shared__ __align__(16) char smem[];
    __bf16* As = (__bf16*)smem;             // 2 x TE
    __bf16* Bs = As + 2 * TE;               // 2 x TE

    int tid = threadIdx.x, lane = tid & 63, wid = tid >> 6;
    int wr = wid >> 2, wc = wid & 3;
    int t = lane & 15, g = lane >> 4;
    int xk2 = ((t >> 1) & 3) * 8;           // fragment-read slot XOR (elems)

    int nwg = gridDim.x, chunk = nwg >> 3;
    int swz = (blockIdx.x & 7) * chunk + (blockIdx.x >> 3);
    int bx = swz % nx, by = swz / nx;
    int rowA0 = by * 256, colB0 = bx * 256;

    int rin = tid >> 2, cblk = tid & 3;     // rin 0..127
    int scol = (cblk ^ ((rin >> 1) & 3)) * 8;   // pre-swizzled source col

    auto stageA = [&](int nb, int kt) {     // 2 gload16 (rows 0-127, 128-255)
        int k0 = kt << 5;
        gload16(A + (size_t)(rowA0 + rin) * K + k0 + scol,
                As + nb * TE + rin * 32 + cblk * 8);
        gload16(A + (size_t)(rowA0 + 128 + rin) * K + k0 + scol,
                As + nb * TE + 4096 + rin * 32 + cblk * 8);
    };
    auto stageB = [&](int nb, int kt) {
        int k0 = kt << 5;
        gload16(Bt + (size_t)(colB0 + rin) * K + k0 + scol,
                Bs + nb * TE + rin * 32 + cblk * 8);
        gload16(Bt + (size_t)(colB0 + 128 + rin) * K + k0 + scol,
                Bs + nb * TE + 4096 + rin * 32 + cblk * 8);
    };

    f32x4 acc[8][4];
#pragma unroll
    for (int m = 0; m < 8; m++)
#pragma unroll
        for (int n = 0; n < 4; n++) acc[m][n] = (f32x4){0.f, 0.f, 0.f, 0.f};

    int NT = K >> 5;
    stageA(0, 0); stageB(0, 0);
    vmwait0();
    barrier_raw();

#pragma unroll 1
    for (int kt = 0; kt < NT; ++kt) {
        int cur = kt & 1, nb = cur ^ 1;
        const __bf16* Ac = As + cur * TE;
        const __bf16* Bc = Bs + cur * TE;
        bool more = (kt + 1) < NT;

        // ---- phase 1: b + a-low reads; stage A(t+1); MFMA m0..3 ----
        bf16x8 b[4], a0[4];
#pragma unroll
        for (int n = 0; n < 4; n++)
            b[n] = *(const bf16x8*)&Bc[(wc * 64 + n * 16 + t) * 32 + ((g * 8) ^ xk2)];
#pragma unroll
        for (int m = 0; m < 4; m++)
            a0[m] = *(const bf16x8*)&Ac[(wr * 128 + m * 16 + t) * 32 + ((g * 8) ^ xk2)];
        if (more) stageA(nb, kt + 1);
        __builtin_amdgcn_s_setprio(1);
#pragma unroll
        for (int m = 0; m < 4; m++)
#pragma unroll
            for (int n = 0; n < 4; n++)
                acc[m][n] = __builtin_amdgcn_mfma_f32_16x16x32_bf16(a0[m], b[n], acc[m][n], 0, 0, 0);
        __builtin_amdgcn_s_setprio(0);

        // ---- phase 2: a-high reads; stage B(t+1); MFMA m4..7 ----
        bf16x8 a1[4];
#pragma unroll
        for (int m = 0; m < 4; m++)
            a1[m] = *(const bf16x8*)&Ac[(wr * 128 + 64 + m * 16 + t) * 32 + ((g * 8) ^ xk2)];
        if (more) stageB(nb, kt + 1);
        __builtin_amdgcn_s_setprio(1);
#pragma unroll
        for (int m = 0; m < 4; m++)
#pragma unroll
            for (int n = 0; n < 4; n++)
                acc[4 + m][n] = __builtin_amdgcn_mfma_f32_16x16x32_bf16(a1[m], b[n], acc[4 + m][n], 0, 0, 0);
        __builtin_amdgcn_s_setprio(0);

        if (more) {
            vmwait0();
            barrier_raw();
        }
    }

    // ---- epilogue ----
    int col0 = colB0 + wc * 64;
    bool vpart = (EP == 0) && (colB0 >= 2048);
#pragma unroll
    for (int m = 0; m < 8; m++)
#pragma unroll
        for (int n = 0; n < 4; n++) {
            int col = col0 + n * 16 + t;
            if (EP == 0 && vpart) {
                int hcol = col - 2048;
                int hh = hcol >> 7, dd = hcol & 127;
                int row0 = rowA0 + wr * 128 + m * 16 + g * 4;
                int bb = row0 >> 10;
                int ntok = row0 & 1023;
                float bs = bias[col];
                ushort4 vv;
                vv.x = f2bf(acc[m][n][0] + bs);
                vv.y = f2bf(acc[m][n][1] + bs);
                vv.z = f2bf(acc[m][n][2] + bs);
                vv.w = f2bf(acc[m][n][3] + bs);
                *(ushort4*)(vt + (((size_t)(bb * 8 + hh) * 128 + dd) * 1024 + ntok)) = vv;
            } else {
#pragma unroll
                for (int r = 0; r < 4; r++) {
                    int row = rowA0 + wr * 128 + m * 16 + g * 4 + r;
                    float v = acc[m][n][r];
                    if (EP == 0) {
                        outb[(size_t)row * N + col] = f2bf(v + bias[col]);
                    } else {
                        outb[(size_t)row * N + col] = f2bf(gelu_fast(v + bias[col]));
                    }
                }
            }
        }
}

// ============ depth-2 prefetch GEMM (NF2): BM=128, BN=128, BK=32 ============
// 256 thr (4 waves 2x2), per-wave 64x64, LDS = 3 x 16KB = 48KB (3 blocks/CU).
// EP: 1 = x+gate*(acc+bias) -> f32, 3 = outf += gate*(acc+bias)
template <int EP>
__global__ __launch_bounds__(256, 4) void gemmo(const unsigned short* __restrict__ A,
                                                const unsigned short* __restrict__ Bt,
                                                int N, int K, int nx,
                                                const float* __restrict__ bias,
                                                const float* __restrict__ xres,
                                                const float* __restrict__ mods,
                                                float* __restrict__ outf) {
    constexpr int AE = 128 * 32;
    constexpr int BE = 128 * 32;
    extern __shared__ __align__(16) char smem[];
    __bf16* As = (__bf16*)smem;             // 3 x AE
    __bf16* Bs = As + 3 * AE;               // 3 x BE

    int tid = threadIdx.x, lane = tid & 63, wid = tid >> 6;
    int wr = wid >> 1, wc = wid & 1;
    int t = lane & 15, g = lane >> 4;
    int xk2 = ((t >> 1) & 3) * 8;

    int nwg = gridDim.x, chunk = nwg >> 3;
    int swz = (blockIdx.x & 7) * chunk + (blockIdx.x >> 3);
    int bx = swz % nx, by = swz / nx;
    int rowA0 = by * 128, colB0 = bx * 128;

    int rin = tid >> 2, cblk = tid & 3;
    int scol = (cblk ^ ((rin >> 1) & 3)) * 8;

    auto stage = [&](int nb, int kt) {          // 4 gload16
        int k0 = kt << 5;
        gload16(A + (size_t)(rowA0 + rin) * K + k0 + scol, As + nb * AE + tid * 8);
        gload16(A + (size_t)(rowA0 + 64 + rin) * K + k0 + scol,
                As + nb * AE + 2048 + tid * 8);
        gload16(Bt + (size_t)(colB0 + rin) * K + k0 + scol, Bs + nb * BE + tid * 8);
        gload16(Bt + (size_t)(colB0 + 64 + rin) * K + k0 + scol,
                Bs + nb * BE + 2048 + tid * 8);
    };

    f32x4 acc[4][4];
#pragma unroll
    for (int m = 0; m < 4; m++)
#pragma unroll
        for (int n = 0; n < 4; n++) acc[m][n] = (f32x4){0.f, 0.f, 0.f, 0.f};

    int NT = K >> 5;
    stage(0, 0);
    if (NT > 1) {
        stage(1, 1);
        asm volatile("s_waitcnt vmcnt(4)" ::: "memory");
    } else {
        vmwait0();
    }
    barrier_raw();

    int cur = 0, tgt = 2;
#pragma unroll 1
    for (int kt = 0; kt < NT; ++kt) {
        bool deep = (kt + 2) < NT;
        bool more = (kt + 1) < NT;
        if (deep) stage(tgt, kt + 2);
        const __bf16* Ac = As + cur * AE;
        const __bf16* Bc = Bs + cur * BE;

        bf16x8 a[4], b[4];
#pragma unroll
        for (int m = 0; m < 4; m++)
            a[m] = *(const bf16x8*)&Ac[(wr * 64 + m * 16 + t) * 32 + ((g * 8) ^ xk2)];
#pragma unroll
        for (int n = 0; n < 4; n++)
            b[n] = *(const bf16x8*)&Bc[(wc * 64 + n * 16 + t) * 32 + ((g * 8) ^ xk2)];

        __builtin_amdgcn_s_setprio(1);
#pragma unroll
        for (int m = 0; m < 4; m++)
#pragma unroll
            for (int n = 0; n < 4; n++)
                acc[m][n] = __builtin_amdgcn_mfma_f32_16x16x32_bf16(a[m], b[n], acc[m][n], 0, 0, 0);
        __builtin_amdgcn_s_setprio(0);

        if (more) {
            if (deep) {
                asm volatile("s_waitcnt vmcnt(4)" ::: "memory");
            } else {
                vmwait0();
            }
            barrier_raw();
        }
        cur = (cur == 2) ? 0 : cur + 1;
        tgt = (tgt == 2) ? 0 : tgt + 1;
    }

    int row0 = rowA0 + wr * 64, col0 = colB0 + wc * 64;
#pragma unroll
    for (int m = 0; m < 4; m++)
#pragma unroll
        for (int n = 0; n < 4; n++) {
            int col = col0 + n * 16 + t;
#pragma unroll
            for (int r = 0; r < 4; r++) {
                int row = row0 + m * 16 + g * 4 + r;
                float v = acc[m][n][r];
                int bb = row >> 10;
                float gt = mods[bb * 3072 + 2048 + col];
                if (EP == 1) {
                    outf[(size_t)row * 1024 + col] =
                        xres[(size_t)row * 1024 + col] + gt * (v + bias[col]);
                } else {
                    outf[(size_t)row * 1024 + col] += gt * (v + bias[col]);
                }
            }
        }
}

// ======== flash attention, swapped-QK^T in-register softmax + defer-max ========
__global__ __launch_bounds__(512, 4) void attn_kernel(const unsigned short* __restrict__ qkv,
                                                      const unsigned short* __restrict__ vt,
                                                      unsigned short* __restrict__ o) {
    extern __shared__ __align__(16) char asmem[];
    __bf16* Ks = (__bf16*)asmem;
    __bf16* Vts = Ks + 2 * 64 * 128;

    int bid = blockIdx.x;
    int logical = (bid & 7) * 64 + (bid >> 3);
    int q0 = (logical & 7) * 128;
    int bh = logical >> 3;
    int b = bh >> 3, h = bh & 7;
    int tid = threadIdx.x, lane = tid & 63, w = tid >> 6;
    int t = lane & 15, g = lane >> 4;
    int swzt = (t & 7) << 4;

    const unsigned short* qbase = qkv + (size_t)(b * 1024) * 3072 + h * 128;
    int qrow = q0 + w * 16 + t;
    bf16x8 qf[4];
#pragma unroll
    for (int ks = 0; ks < 4; ks++)
        qf[ks] = *(const bf16x8*)(qbase + (size_t)qrow * 3072 + ks * 32 + g * 8);

    f32x4 Oa[8];
#pragma unroll
    for (int n = 0; n < 8; n++) Oa[n] = (f32x4){0.f, 0.f, 0.f, 0.f};
    float m_r = -1e30f, l_r = 0.f;
    const float scale = 0.08838834764831845f;

    int krow = tid >> 4;
    int ksrc = (((tid & 15) * 16) ^ ((krow & 7) << 4)) >> 1;
    int vrow = tid >> 3;
    int vsrc = (((tid & 7) * 16) ^ ((vrow & 7) << 4)) >> 1;
    const unsigned short* vtg = vt + (size_t)bh * 128 * 1024;

    auto stage = [&](int buf, int kv0) {
        const unsigned short* kb = qkv + (size_t)(b * 1024 + kv0) * 3072 + 1024 + h * 128;
#pragma unroll
        for (int cc = 0; cc < 2; cc++) {
            gload16(kb + (size_t)(cc * 32 + krow) * 3072 + ksrc,
                    (void*)(Ks + buf * 8192 + cc * 4096 + tid * 8));
            gload16(vtg + (size_t)(cc * 64 + vrow) * 1024 + kv0 + vsrc,
                    (void*)(Vts + buf * 8192 + cc * 4096 + tid * 8));
        }
    };

    stage(0, 0);
    vmwait0();
    barrier_raw();

#pragma unroll 1
    for (int tile = 0; tile < 16; ++tile) {
        int cur = tile & 1;
        bool more = tile < 15;
        if (more) stage(cur ^ 1, (tile + 1) * 64);
        const __bf16* Kc = Ks + cur * 8192;
        const __bf16* Vc = Vts + cur * 8192;

        f32x4 St[4];
#pragma unroll
        for (int n = 0; n < 4; n++) St[n] = (f32x4){0.f, 0.f, 0.f, 0.f};
        __builtin_amdgcn_s_setprio(1);
#pragma unroll
        for (int ks = 0; ks < 4; ks++) {
#pragma unroll
            for (int n = 0; n < 4; n++) {
                bf16x8 kf = *(const bf16x8*)&Kc[(n * 16 + t) * 128 + (((ks * 64 + g * 16) ^ swzt) >> 1)];
                St[n] = __builtin_amdgcn_mfma_f32_16x16x32_bf16(kf, qf[ks], St[n], 0, 0, 0);
            }
        }
        __builtin_amdgcn_s_setprio(0);

        float mx = -1e30f;
#pragma unroll
        for (int n = 0; n < 4; n++)
#pragma unroll
            for (int r = 0; r < 4; r++) mx = fmaxf(mx, St[n][r]);
        mx *= scale;
        mx = fmaxf(mx, __shfl_xor(mx, 16));
        mx = fmaxf(mx, __shfl_xor(mx, 32));
        // defer-max (T13): only rescale when the running max moved by > 8
        if (!__all(mx - m_r <= 8.f)) {
            float mn = fmaxf(m_r, mx);
            float alpha = __expf(m_r - mn);
            m_r = mn;
            l_r *= alpha;
#pragma unroll
            for (int r = 0; r < 4; r++) {
                float ar = __shfl(alpha, (lane & 48) + g * 4 + r);
#pragma unroll
                for (int n2 = 0; n2 < 8; n2++) Oa[n2][r] *= ar;
            }
        }
        float p[4][4];
        float rs = 0.f;
#pragma unroll
        for (int n = 0; n < 4; n++)
#pragma unroll
            for (int r = 0; r < 4; r++) {
                float pv = __expf(St[n][r] * scale - m_r);
                p[n][r] = pv;
                rs += pv;
            }
        rs += __shfl_xor(rs, 16);
        rs += __shfl_xor(rs, 32);
        l_r += rs;

        unsigned P01[4], P23[4];
#pragma unroll
        for (int n = 0; n < 4; n++) {
            P01[n] = (unsigned)f2bf(p[n][0]) | ((unsigned)f2bf(p[n][1]) << 16);
            P23[n] = (unsigned)f2bf(p[n][2]) | ((unsigned)f2bf(p[n][3]) << 16);
        }

#pragma unroll
        for (int ks2 = 0; ks2 < 2; ks2++) {
            int e = ks2 * 2, od = ks2 * 2 + 1;
            unsigned s16a = (g < 2) ? P01[e] : P01[od];
            unsigned s16b = (g < 2) ? P23[e] : P23[od];
            unsigned s32a = (g & 1) ? P01[e] : P01[od];
            unsigned s32b = (g & 1) ? P23[e] : P23[od];
            unsigned s48a = (g >= 2) ? P01[e] : P01[od];
            unsigned s48b = (g >= 2) ? P23[e] : P23[od];
            unsigned r16a = __shfl_xor(s16a, 16), r16b = __shfl_xor(s16b, 16);
            unsigned r32a = __shfl_xor(s32a, 32), r32b = __shfl_xor(s32b, 32);
            unsigned r48a = __shfl_xor(s48a, 48), r48b = __shfl_xor(s48b, 48);
            union { unsigned u[4]; bf16x8 v; } pa;
            pa.u[0] = (g == 0) ? P01[e] : (g == 1) ? r48a : (g == 2) ? r32a : r16a;
            pa.u[1] = (g == 0) ? P23[e] : (g == 1) ? r48b : (g == 2) ? r32b : r16b;
            pa.u[2] = (g == 0) ? r16a : (g == 1) ? r32a : (g == 2) ? r48a : P01[od];
            pa.u[3] = (g == 0) ? r16b : (g == 1) ? r32b : (g == 2) ? r48b : P23[od];
            __builtin_amdgcn_s_setprio(1);
#pragma unroll
            for (int n2 = 0; n2 < 8; n2++) {
                bf16x8 vf = *(const bf16x8*)&Vc[(n2 * 16 + t) * 64 + (((ks2 * 64 + g * 16) ^ swzt) >> 1)];
                Oa[n2] = __builtin_amdgcn_mfma_f32_16x16x32_bf16(pa.v, vf, Oa[n2], 0, 0, 0);
            }
            __builtin_amdgcn_s_setprio(0);
        }

        if (more) {
            vmwait0();
            barrier_raw();
        }
    }

#pragma unroll
    for (int r = 0; r < 4; r++) {
        float lq = __shfl(l_r, (lane & 48) + g * 4 + r);
        float inv = 1.f / lq;
        int orow = q0 + w * 16 + g * 4 + r;
#pragma unroll
        for (int n2 = 0; n2 < 8; n2++)
            o[(size_t)(b * 1024 + orow) * 1024 + h * 128 + n2 * 16 + t] = f2bf(Oa[n2][r] * inv);
    }
}

extern "C" void kernel_launch(void* const* d_in, const int* in_sizes, int n_in,
                              void* d_out, int out_size, void* d_ws, size_t ws_size,
                              hipStream_t stream) {
    const float* x          = (const float*)d_in[0];
    const float* c          = (const float*)d_in[1];
    const float* m_ada_w    = (const float*)d_in[2];
    const float* m_ada_b    = (const float*)d_in[3];
    const float* m_norm_g   = (const float*)d_in[4];
    const float* m_norm_b   = (const float*)d_in[5];
    const float* in_proj_w  = (const float*)d_in[6];
    const float* in_proj_b  = (const float*)d_in[7];
    const float* out_proj_w = (const float*)d_in[8];
    const float* out_proj_b = (const float*)d_in[9];
    const float* f_ada_w    = (const float*)d_in[10];
    const float* f_ada_b    = (const float*)d_in[11];
    const float* f_norm_g   = (const float*)d_in[12];
    const float* f_norm_b   = (const float*)d_in[13];
    const float* w1         = (const float*)d_in[14];
    const float* b1         = (const float*)d_in[15];
    const float* w2         = (const float*)d_in[16];
    const float* b2         = (const float*)d_in[17];
    float* out = (float*)d_out;
    char* ws = (char*)d_ws;

    unsigned short* Wq   = (unsigned short*)(ws + 0);          // 3072x1024 bf16
    unsigned short* Wo   = (unsigned short*)(ws + 6291456);    // 1024x1024
    unsigned short* vt   = (unsigned short*)(ws + 8388608);    // 64x128x1024 (later W1t/W2t)
    unsigned short* W1t  = (unsigned short*)(ws + 8388608);    // 4096x1024
    unsigned short* W2t  = (unsigned short*)(ws + 16777216);   // 1024x4096
    float*          modm = (float*)(ws + 25165824);            // 8x3072
    float*          modf = (float*)(ws + 25264128);            // 8x3072
    unsigned short* hbuf = (unsigned short*)(ws + 25362432);   // 8192x1024
    float*          part = (float*)(ws + 25362432);            // ada partials (hbuf region)
    float*          part2= (float*)(ws + 25362432 + 2097152);
    unsigned short* qkv  = (unsigned short*)(ws + 42139648);   // 8192x3072
    unsigned short* obuf = (unsigned short*)(ws + 92471296);   // 8192x1024
    unsigned short* h2   = (unsigned short*)(ws + 42139648);   // 8192x4096 (aliases qkv+obuf)

    hipFuncSetAttribute((const void*)&gemm9<0>, hipFuncAttributeMaxDynamicSharedMemorySize, 65536);
    hipFuncSetAttribute((const void*)&gemm9<2>, hipFuncAttributeMaxDynamicSharedMemorySize, 65536);
    hipFuncSetAttribute((const void*)&gemmo<1>, hipFuncAttributeMaxDynamicSharedMemorySize, 49152);
    hipFuncSetAttribute((const void*)&gemmo<3>, hipFuncAttributeMaxDynamicSharedMemorySize, 49152);
    hipFuncSetAttribute((const void*)&attn_kernel, hipFuncAttributeMaxDynamicSharedMemorySize, 65536);

    hipLaunchKernelGGL(ada_mod_part, dim3(12, 16, 2), dim3(256), 0, stream,
                       c, m_ada_w, f_ada_w, part, part2);
    hipLaunchKernelGGL(ada_reduce, dim3(96, 2), dim3(256), 0, stream,
                       part, part2, m_ada_b, f_ada_b, modm, modf);

    hipLaunchKernelGGL(f2b4, dim3(3072), dim3(256), 0, stream, in_proj_w, Wq);
    hipLaunchKernelGGL(f2b4, dim3(1024), dim3(256), 0, stream, out_proj_w, Wo);

    hipLaunchKernelGGL(ln_mod_kernel, dim3(8192), dim3(256), 0, stream, x, m_norm_g, m_norm_b, modm, hbuf);
    // qkv: 32 row-panels x 12 cols = 384 blocks; V cols write vt directly
    hipLaunchKernelGGL(HIP_KERNEL_NAME(gemm9<0>), dim3(384), dim3(512), 65536, stream,
                       hbuf, Wq, 3072, 1024, 12, in_proj_b, qkv, vt);
    hipLaunchKernelGGL(attn_kernel, dim3(512), dim3(512), 65536, stream, qkv, vt, obuf);
    // out-proj: 64 x 8 = 512 blocks
    hipLaunchKernelGGL(HIP_KERNEL_NAME(gemmo<1>), dim3(512), dim3(256), 49152, stream,
                       obuf, Wo, 1024, 1024, 8, out_proj_b, x, modm, out);

    hipLaunchKernelGGL(transpose_f2b, dim3(128, 32), dim3(256), 0, stream, w1, W1t, 1024, 4096);
    hipLaunchKernelGGL(transpose_f2b, dim3(32, 128), dim3(256), 0, stream, w2, W2t, 4096, 1024);

    hipLaunchKernelGGL(ln_mod_kernel, dim3(8192), dim3(256), 0, stream, out, f_norm_g, f_norm_b, modf, hbuf);
    // FF1: 32 x 16 = 512 blocks
    hipLaunchKernelGGL(HIP_KERNEL_NAME(gemm9<2>), dim3(512), dim3(512), 65536, stream,
                       hbuf, W1t, 4096, 1024, 16, b1, h2, (unsigned short*)nullptr);
    // FF2: K=4096, 64 x 8 = 512 blocks
    hipLaunchKernelGGL(HIP_KERNEL_NAME(gemmo<3>), dim3(512), dim3(256), 49152, stream,
                       h2, W2t, 1024, 4096, 8, b2, (const float*)nullptr, modf, out);
}

// Round 13
// 369.028 us; speedup vs baseline: 1.0681x; 1.0237x over previous
//
#include <hip/hip_runtime.h>

typedef __bf16 bf16x8 __attribute__((ext_vector_type(8)));
typedef float f32x4 __attribute__((ext_vector_type(4)));

__device__ __forceinline__ unsigned short f2bf(float f) {
    unsigned int u = __float_as_uint(f);
    unsigned int r = (u + 0x7FFFu + ((u >> 16) & 1u)) >> 16;
    return (unsigned short)r;
}

__device__ __forceinline__ void gload16(const void* g, void* l) {
    __builtin_amdgcn_global_load_lds(
        (const __attribute__((address_space(1))) unsigned int*)g,
        (__attribute__((address_space(3))) unsigned int*)l, 16, 0, 0);
}

__device__ __forceinline__ void barrier_raw() {
    asm volatile("" ::: "memory");
    __builtin_amdgcn_s_barrier();
    asm volatile("" ::: "memory");
}

__device__ __forceinline__ void vmwait0() {
    asm volatile("s_waitcnt vmcnt(0)" ::: "memory");
}

__device__ __forceinline__ float gelu_fast(float u) {
    float z = 1.595769122f * u + 0.071354816f * u * u * u;
    return u / (1.f + __expf(-z));
}

// ---------------- weight convert: fp32 -> bf16, 4 elems/thread ----------------
__global__ __launch_bounds__(256) void f2b4(const float* __restrict__ in,
                                            unsigned short* __restrict__ out) {
    size_t i = ((size_t)blockIdx.x * 256 + threadIdx.x) * 4;
    float4 v = *(const float4*)(in + i);
    ushort4 o;
    o.x = f2bf(v.x); o.y = f2bf(v.y); o.z = f2bf(v.z); o.w = f2bf(v.w);
    *(ushort4*)(out + i) = o;
}

// ------------- transpose + convert: fp32 [R][C] -> bf16 [C][R] ---------------
__global__ __launch_bounds__(256) void transpose_f2b(const float* __restrict__ in,
                                                     unsigned short* __restrict__ out,
                                                     int R, int C) {
    __shared__ float tile[32][33];
    int r0 = blockIdx.y * 32, c0 = blockIdx.x * 32;
    int tx = threadIdx.x & 31, ty = threadIdx.x >> 5;
#pragma unroll
    for (int i = 0; i < 4; i++) {
        int r = ty + i * 8;
        tile[r][tx] = in[(size_t)(r0 + r) * C + c0 + tx];
    }
    __syncthreads();
#pragma unroll
    for (int i = 0; i < 4; i++) {
        int r = ty + i * 8;
        out[(size_t)(c0 + r) * R + r0 + tx] = f2bf(tile[tx][r]);
    }
}

// -------- ada modulation, split-K, both branches in one launch (z = m/f) --------
__global__ __launch_bounds__(256) void ada_mod_part(const float* __restrict__ c,
                                                    const float* __restrict__ W0,
                                                    const float* __restrict__ W1,
                                                    float* __restrict__ p0,
                                                    float* __restrict__ p1) {
    const float* W = blockIdx.z ? W1 : W0;
    float* partial = blockIdx.z ? p1 : p0;
    __shared__ float sc[8 * 64];
    int kc = blockIdx.y * 64;
    for (int i = threadIdx.x; i < 512; i += 256) {
        int b = i >> 6, k = i & 63;
        float cv = c[b * 1024 + kc + k];
        sc[i] = cv / (1.f + __expf(-cv));
    }
    __syncthreads();
    int j = blockIdx.x * 256 + threadIdx.x;
    float acc[8] = {0, 0, 0, 0, 0, 0, 0, 0};
    for (int k = 0; k < 64; k++) {
        float w = W[(size_t)(kc + k) * 3072 + j];
#pragma unroll
        for (int b = 0; b < 8; b++) acc[b] += sc[b * 64 + k] * w;
    }
#pragma unroll
    for (int b = 0; b < 8; b++) partial[((size_t)blockIdx.y * 8 + b) * 3072 + j] = acc[b];
}

__global__ __launch_bounds__(256) void ada_reduce(const float* __restrict__ p0,
                                                  const float* __restrict__ p1,
                                                  const float* __restrict__ b0,
                                                  const float* __restrict__ b1,
                                                  float* __restrict__ o0,
                                                  float* __restrict__ o1) {
    const float* partial = blockIdx.y ? p1 : p0;
    const float* bias = blockIdx.y ? b1 : b0;
    float* out = blockIdx.y ? o1 : o0;
    int idx = blockIdx.x * 256 + threadIdx.x;
    int b = idx / 3072;
    int jj = idx - b * 3072;
    float s = bias[jj];
#pragma unroll
    for (int ch = 0; ch < 16; ch++) s += partial[((size_t)ch * 8 + b) * 3072 + jj];
    out[idx] = s;
}

// -------- LN + adaLN modulate: fp32 row -> bf16 row --------
__global__ __launch_bounds__(256) void ln_mod_kernel(const float* __restrict__ x,
                                                     const float* __restrict__ gamma,
                                                     const float* __restrict__ beta,
                                                     const float* __restrict__ mods,
                                                     unsigned short* __restrict__ out) {
    int row = blockIdx.x;
    int b = row >> 10;
    float4 v = ((const float4*)(x + (size_t)row * 1024))[threadIdx.x];
    float s = v.x + v.y + v.z + v.w;
    float s2 = v.x * v.x + v.y * v.y + v.z * v.z + v.w * v.w;
#pragma unroll
    for (int d = 1; d < 64; d <<= 1) { s += __shfl_xor(s, d); s2 += __shfl_xor(s2, d); }
    __shared__ float red[8];
    int lane = threadIdx.x & 63, wid = threadIdx.x >> 6;
    if (lane == 0) { red[wid] = s; red[4 + wid] = s2; }
    __syncthreads();
    float S = red[0] + red[1] + red[2] + red[3];
    float S2 = red[4] + red[5] + red[6] + red[7];
    float mu = S * (1.f / 1024.f);
    float var = S2 * (1.f / 1024.f) - mu * mu;
    float rs = rsqrtf(var + 1e-6f);
    const float* mrow = mods + b * 3072;
    int j0 = threadIdx.x * 4;
    float hv[4] = {v.x, v.y, v.z, v.w};
    ushort4 o;
    unsigned short* op = (unsigned short*)&o;
#pragma unroll
    for (int i = 0; i < 4; i++) {
        int j = j0 + i;
        float hh = (hv[i] - mu) * rs * gamma[j] + beta[j];
        hh = hh * (1.f + mrow[1024 + j]) + mrow[j];
        op[i] = f2bf(hh);
    }
    *(ushort4*)(out + (size_t)row * 1024 + j0) = o;
}

// ============ big-tile multi-block GEMM, compile-time addressing ============
// BM=BN=256, BK=32, 512 thr (8 waves 2x4, per-wave 128x64).  LDS 64KB (2 dbuf)
// -> 2 blocks/CU.  K-loop UNROLLED x2 so the dbuf index is COMPILE-TIME:
// all 16 ds_read + 4 ds-dest addresses become immediates off one per-lane base
// register (kills the ~40% VALU issue share that capped MfmaUtil at ~30%).
// 64B LDS rows, (row>>1)&3 16B-slot XOR (0 conflicts), source pre-swizzled.
// EP: 0 = +bias -> bf16 (cols>=2048 write V^T to vt), 2 = gelu(acc+bias) -> bf16
template <int EP>
__global__ __launch_bounds__(512, 2) void gemm9(const unsigned short* __restrict__ A,
                                                const unsigned short* __restrict__ Bt,
                                                int N, int K, int nx,
                                                const float* __restrict__ bias,
                                                unsigned short* __restrict__ outb,
                                                unsigned short* __restrict__ vt) {
    constexpr int TE = 256 * 32;            // 8192 elems per operand buffer (16KB)
    extern __shared__ __align__(16) char smem[];
    __bf16* As = (__bf16*)smem;             // 2 x TE
    __bf16* Bs = As + 2 * TE;               // 2 x TE

    int tid = threadIdx.x, lane = tid & 63, wid = tid >> 6;
    int wr = wid >> 2, wc = wid & 3;
    int t = lane & 15, g = lane >> 4;
    int xk2 = ((t >> 1) & 3) * 8;

    int nwg = gridDim.x, chunk = nwg >> 3;
    int swz = (blockIdx.x & 7) * chunk + (blockIdx.x >> 3);
    int bx = swz % nx, by = swz / nx;
    int rowA0 = by * 256, colB0 = bx * 256;

    int rin = tid >> 2, cblk = tid & 3;
    int scol = (cblk ^ ((rin >> 1) & 3)) * 8;

    // hoisted per-lane bases (all loop addressing = base + compile-time offset)
    const __bf16* a_rd = As + (wr * 128 + t) * 32 + ((g * 8) ^ xk2);
    const __bf16* b_rd = Bs + (wc * 64 + t) * 32 + ((g * 8) ^ xk2);
    __bf16* a_wr = As + rin * 32 + cblk * 8;
    __bf16* b_wr = Bs + rin * 32 + cblk * 8;
    const unsigned short* pa = A + (size_t)(rowA0 + rin) * K + scol;
    const unsigned short* pb = Bt + (size_t)(colB0 + rin) * K + scol;
    const size_t aStep = (size_t)128 * K;

    f32x4 acc[8][4];
#pragma unroll
    for (int m = 0; m < 8; m++)
#pragma unroll
        for (int n = 0; n < 4; n++) acc[m][n] = (f32x4){0.f, 0.f, 0.f, 0.f};

    int NT = K >> 5;   // always even (K = 1024 or 4096)
    // prologue: stage tile 0 into buf 0
    gload16(pa, a_wr); gload16(pa + aStep, a_wr + 4096);
    gload16(pb, b_wr); gload16(pb + aStep, b_wr + 4096);
    vmwait0();
    barrier_raw();

#define G9_BODY(CUR)                                                                     \
    {                                                                                    \
        constexpr int NB = CUR ^ 1;                                                      \
        bool more = (kt + 1) < NT;                                                       \
        const unsigned short* sa = pa + (kt + 1) * 32;                                   \
        const unsigned short* sb = pb + (kt + 1) * 32;                                   \
        bf16x8 b[4], a0[4];                                                              \
        _Pragma("unroll")                                                                \
        for (int n = 0; n < 4; n++) b[n] = *(const bf16x8*)(b_rd + CUR * TE + n * 512);  \
        _Pragma("unroll")                                                                \
        for (int m = 0; m < 4; m++) a0[m] = *(const bf16x8*)(a_rd + CUR * TE + m * 512); \
        if (more) { gload16(sa, a_wr + NB * TE); gload16(sa + aStep, a_wr + NB * TE + 4096); } \
        __builtin_amdgcn_s_setprio(1);                                                   \
        _Pragma("unroll")                                                                \
        for (int m = 0; m < 4; m++)                                                      \
            _Pragma("unroll")                                                            \
            for (int n = 0; n < 4; n++)                                                  \
                acc[m][n] = __builtin_amdgcn_mfma_f32_16x16x32_bf16(a0[m], b[n], acc[m][n], 0, 0, 0); \
        __builtin_amdgcn_s_setprio(0);                                                   \
        bf16x8 a1[4];                                                                    \
        _Pragma("unroll")                                                                \
        for (int m = 0; m < 4; m++)                                                      \
            a1[m] = *(const bf16x8*)(a_rd + CUR * TE + 2048 + m * 512);                  \
        if (more) { gload16(sb, b_wr + NB * TE); gload16(sb + aStep, b_wr + NB * TE + 4096); } \
        __builtin_amdgcn_s_setprio(1);                                                   \
        _Pragma("unroll")                                                                \
        for (int m = 0; m < 4; m++)                                                      \
            _Pragma("unroll")                                                            \
            for (int n = 0; n < 4; n++)                                                  \
                acc[4 + m][n] = __builtin_amdgcn_mfma_f32_16x16x32_bf16(a1[m], b[n], acc[4 + m][n], 0, 0, 0); \
        __builtin_amdgcn_s_setprio(0);                                                   \
        if (more) { vmwait0(); barrier_raw(); }                                          \
    }

#pragma unroll 1
    for (int kt = 0; kt < NT; kt += 2) {
        G9_BODY(0)
        ++kt;
        G9_BODY(1)
        --kt;
    }
#undef G9_BODY

    // ---- epilogue ----
    int col0 = colB0 + wc * 64;
    bool vpart = (EP == 0) && (colB0 >= 2048);
#pragma unroll
    for (int m = 0; m < 8; m++)
#pragma unroll
        for (int n = 0; n < 4; n++) {
            int col = col0 + n * 16 + t;
            if (EP == 0 && vpart) {
                int hcol = col - 2048;
                int hh = hcol >> 7, dd = hcol & 127;
                int row0 = rowA0 + wr * 128 + m * 16 + g * 4;
                int bb = row0 >> 10;
                int ntok = row0 & 1023;
                float bs = bias[col];
                ushort4 vv;
                vv.x = f2bf(acc[m][n][0] + bs);
                vv.y = f2bf(acc[m][n][1] + bs);
                vv.z = f2bf(acc[m][n][2] + bs);
                vv.w = f2bf(acc[m][n][3] + bs);
                *(ushort4*)(vt + (((size_t)(bb * 8 + hh) * 128 + dd) * 1024 + ntok)) = vv;
            } else {
#pragma unroll
                for (int r = 0; r < 4; r++) {
                    int row = rowA0 + wr * 128 + m * 16 + g * 4 + r;
                    float v = acc[m][n][r];
                    if (EP == 0) {
                        outb[(size_t)row * N + col] = f2bf(v + bias[col]);
                    } else {
                        outb[(size_t)row * N + col] = f2bf(gelu_fast(v + bias[col]));
                    }
                }
            }
        }
}

// ============ NF2 GEMM, compile-time addressing: BM=128, BN=128, BK=32 ============
// 256 thr (4 waves 2x2), per-wave 64x64, LDS = 2 x 16KB = 32KB (4 blocks/CU).
// K-loop unrolled x2 (compile-time dbuf).  EP: 1 = x+gate*(acc+bias) -> f32,
// 3 = outf += gate*(acc+bias)
template <int EP>
__global__ __launch_bounds__(256, 4) void gemmo(const unsigned short* __restrict__ A,
                                                const unsigned short* __restrict__ Bt,
                                                int N, int K, int nx,
                                                const float* __restrict__ bias,
                                                const float* __restrict__ xres,
                                                const float* __restrict__ mods,
                                                float* __restrict__ outf) {
    constexpr int TE = 128 * 32;            // 4096 elems per operand buffer (8KB)
    extern __shared__ __align__(16) char smem[];
    __bf16* As = (__bf16*)smem;             // 2 x TE
    __bf16* Bs = As + 2 * TE;               // 2 x TE

    int tid = threadIdx.x, lane = tid & 63, wid = tid >> 6;
    int wr = wid >> 1, wc = wid & 1;
    int t = lane & 15, g = lane >> 4;
    int xk2 = ((t >> 1) & 3) * 8;

    int nwg = gridDim.x, chunk = nwg >> 3;
    int swz = (blockIdx.x & 7) * chunk + (blockIdx.x >> 3);
    int bx = swz % nx, by = swz / nx;
    int rowA0 = by * 128, colB0 = bx * 128;

    int rin = tid >> 2, cblk = tid & 3;
    int scol = (cblk ^ ((rin >> 1) & 3)) * 8;

    const __bf16* a_rd = As + (wr * 64 + t) * 32 + ((g * 8) ^ xk2);
    const __bf16* b_rd = Bs + (wc * 64 + t) * 32 + ((g * 8) ^ xk2);
    __bf16* a_wr = As + rin * 32 + cblk * 8;
    __bf16* b_wr = Bs + rin * 32 + cblk * 8;
    const unsigned short* pa = A + (size_t)(rowA0 + rin) * K + scol;
    const unsigned short* pb = Bt + (size_t)(colB0 + rin) * K + scol;
    const size_t hStep = (size_t)64 * K;

    f32x4 acc[4][4];
#pragma unroll
    for (int m = 0; m < 4; m++)
#pragma unroll
        for (int n = 0; n < 4; n++) acc[m][n] = (f32x4){0.f, 0.f, 0.f, 0.f};

    int NT = K >> 5;
    gload16(pa, a_wr); gload16(pa + hStep, a_wr + 2048);
    gload16(pb, b_wr); gload16(pb + hStep, b_wr + 2048);
    vmwait0();
    barrier_raw();

#define GO_BODY(CUR)                                                                     \
    {                                                                                    \
        constexpr int NB = CUR ^ 1;                                                      \
        bool more = (kt + 1) < NT;                                                       \
        const unsigned short* sa = pa + (kt + 1) * 32;                                   \
        const unsigned short* sb = pb + (kt + 1) * 32;                                   \
        if (more) {                                                                      \
            gload16(sa, a_wr + NB * TE); gload16(sa + hStep, a_wr + NB * TE + 2048);     \
            gload16(sb, b_wr + NB * TE); gload16(sb + hStep, b_wr + NB * TE + 2048);     \
        }                                                                                \
        bf16x8 a[4], b[4];                                                               \
        _Pragma("unroll")                                                                \
        for (int m = 0; m < 4; m++) a[m] = *(const bf16x8*)(a_rd + CUR * TE + m * 512);  \
        _Pragma("unroll")                                                                \
        for (int n = 0; n < 4; n++) b[n] = *(const bf16x8*)(b_rd + CUR * TE + n * 512);  \
        __builtin_amdgcn_s_setprio(1);                                                   \
        _Pragma("unroll")                                                                \
        for (int m = 0; m < 4; m++)                                                      \
            _Pragma("unroll")                                                            \
            for (int n = 0; n < 4; n++)                                                  \
                acc[m][n] = __builtin_amdgcn_mfma_f32_16x16x32_bf16(a[m], b[n], acc[m][n], 0, 0, 0); \
        __builtin_amdgcn_s_setprio(0);                                                   \
        if (more) { vmwait0(); barrier_raw(); }                                          \
    }

#pragma unroll 1
    for (int kt = 0; kt < NT; kt += 2) {
        GO_BODY(0)
        ++kt;
        GO_BODY(1)
        --kt;
    }
#undef GO_BODY

    int row0 = rowA0 + wr * 64, col0 = colB0 + wc * 64;
#pragma unroll
    for (int m = 0; m < 4; m++)
#pragma unroll
        for (int n = 0; n < 4; n++) {
            int col = col0 + n * 16 + t;
#pragma unroll
            for (int r = 0; r < 4; r++) {
                int row = row0 + m * 16 + g * 4 + r;
                float v = acc[m][n][r];
                int bb = row >> 10;
                float gt = mods[bb * 3072 + 2048 + col];
                if (EP == 1) {
                    outf[(size_t)row * 1024 + col] =
                        xres[(size_t)row * 1024 + col] + gt * (v + bias[col]);
                } else {
                    outf[(size_t)row * 1024 + col] += gt * (v + bias[col]);
                }
            }
        }
}

// ======== flash attention, swapped-QK^T in-register softmax + defer-max ========
__global__ __launch_bounds__(512, 4) void attn_kernel(const unsigned short* __restrict__ qkv,
                                                      const unsigned short* __restrict__ vt,
                                                      unsigned short* __restrict__ o) {
    extern __shared__ __align__(16) char asmem[];
    __bf16* Ks = (__bf16*)asmem;
    __bf16* Vts = Ks + 2 * 64 * 128;

    int bid = blockIdx.x;
    int logical = (bid & 7) * 64 + (bid >> 3);
    int q0 = (logical & 7) * 128;
    int bh = logical >> 3;
    int b = bh >> 3, h = bh & 7;
    int tid = threadIdx.x, lane = tid & 63, w = tid >> 6;
    int t = lane & 15, g = lane >> 4;
    int swzt = (t & 7) << 4;

    const unsigned short* qbase = qkv + (size_t)(b * 1024) * 3072 + h * 128;
    int qrow = q0 + w * 16 + t;
    bf16x8 qf[4];
#pragma unroll
    for (int ks = 0; ks < 4; ks++)
        qf[ks] = *(const bf16x8*)(qbase + (size_t)qrow * 3072 + ks * 32 + g * 8);

    f32x4 Oa[8];
#pragma unroll
    for (int n = 0; n < 8; n++) Oa[n] = (f32x4){0.f, 0.f, 0.f, 0.f};
    float m_r = -1e30f, l_r = 0.f;
    const float scale = 0.08838834764831845f;

    int krow = tid >> 4;
    int ksrc = (((tid & 15) * 16) ^ ((krow & 7) << 4)) >> 1;
    int vrow = tid >> 3;
    int vsrc = (((tid & 7) * 16) ^ ((vrow & 7) << 4)) >> 1;
    const unsigned short* vtg = vt + (size_t)bh * 128 * 1024;

    auto stage = [&](int buf, int kv0) {
        const unsigned short* kb = qkv + (size_t)(b * 1024 + kv0) * 3072 + 1024 + h * 128;
#pragma unroll
        for (int cc = 0; cc < 2; cc++) {
            gload16(kb + (size_t)(cc * 32 + krow) * 3072 + ksrc,
                    (void*)(Ks + buf * 8192 + cc * 4096 + tid * 8));
            gload16(vtg + (size_t)(cc * 64 + vrow) * 1024 + kv0 + vsrc,
                    (void*)(Vts + buf * 8192 + cc * 4096 + tid * 8));
        }
    };

    stage(0, 0);
    vmwait0();
    barrier_raw();

#pragma unroll 1
    for (int tile = 0; tile < 16; ++tile) {
        int cur = tile & 1;
        bool more = tile < 15;
        if (more) stage(cur ^ 1, (tile + 1) * 64);
        const __bf16* Kc = Ks + cur * 8192;
        const __bf16* Vc = Vts + cur * 8192;

        f32x4 St[4];
#pragma unroll
        for (int n = 0; n < 4; n++) St[n] = (f32x4){0.f, 0.f, 0.f, 0.f};
        __builtin_amdgcn_s_setprio(1);
#pragma unroll
        for (int ks = 0; ks < 4; ks++) {
#pragma unroll
            for (int n = 0; n < 4; n++) {
                bf16x8 kf = *(const bf16x8*)&Kc[(n * 16 + t) * 128 + (((ks * 64 + g * 16) ^ swzt) >> 1)];
                St[n] = __builtin_amdgcn_mfma_f32_16x16x32_bf16(kf, qf[ks], St[n], 0, 0, 0);
            }
        }
        __builtin_amdgcn_s_setprio(0);

        float mx = -1e30f;
#pragma unroll
        for (int n = 0; n < 4; n++)
#pragma unroll
            for (int r = 0; r < 4; r++) mx = fmaxf(mx, St[n][r]);
        mx *= scale;
        mx = fmaxf(mx, __shfl_xor(mx, 16));
        mx = fmaxf(mx, __shfl_xor(mx, 32));
        if (!__all(mx - m_r <= 8.f)) {
            float mn = fmaxf(m_r, mx);
            float alpha = __expf(m_r - mn);
            m_r = mn;
            l_r *= alpha;
#pragma unroll
            for (int r = 0; r < 4; r++) {
                float ar = __shfl(alpha, (lane & 48) + g * 4 + r);
#pragma unroll
                for (int n2 = 0; n2 < 8; n2++) Oa[n2][r] *= ar;
            }
        }
        float p[4][4];
        float rs = 0.f;
#pragma unroll
        for (int n = 0; n < 4; n++)
#pragma unroll
            for (int r = 0; r < 4; r++) {
                float pv = __expf(St[n][r] * scale - m_r);
                p[n][r] = pv;
                rs += pv;
            }
        rs += __shfl_xor(rs, 16);
        rs += __shfl_xor(rs, 32);
        l_r += rs;

        unsigned P01[4], P23[4];
#pragma unroll
        for (int n = 0; n < 4; n++) {
            P01[n] = (unsigned)f2bf(p[n][0]) | ((unsigned)f2bf(p[n][1]) << 16);
            P23[n] = (unsigned)f2bf(p[n][2]) | ((unsigned)f2bf(p[n][3]) << 16);
        }

#pragma unroll
        for (int ks2 = 0; ks2 < 2; ks2++) {
            int e = ks2 * 2, od = ks2 * 2 + 1;
            unsigned s16a = (g < 2) ? P01[e] : P01[od];
            unsigned s16b = (g < 2) ? P23[e] : P23[od];
            unsigned s32a = (g & 1) ? P01[e] : P01[od];
            unsigned s32b = (g & 1) ? P23[e] : P23[od];
            unsigned s48a = (g >= 2) ? P01[e] : P01[od];
            unsigned s48b = (g >= 2) ? P23[e] : P23[od];
            unsigned r16a = __shfl_xor(s16a, 16), r16b = __shfl_xor(s16b, 16);
            unsigned r32a = __shfl_xor(s32a, 32), r32b = __shfl_xor(s32b, 32);
            unsigned r48a = __shfl_xor(s48a, 48), r48b = __shfl_xor(s48b, 48);
            union { unsigned u[4]; bf16x8 v; } pa;
            pa.u[0] = (g == 0) ? P01[e] : (g == 1) ? r48a : (g == 2) ? r32a : r16a;
            pa.u[1] = (g == 0) ? P23[e] : (g == 1) ? r48b : (g == 2) ? r32b : r16b;
            pa.u[2] = (g == 0) ? r16a : (g == 1) ? r32a : (g == 2) ? r48a : P01[od];
            pa.u[3] = (g == 0) ? r16b : (g == 1) ? r32b : (g == 2) ? r48b : P23[od];
            __builtin_amdgcn_s_setprio(1);
#pragma unroll
            for (int n2 = 0; n2 < 8; n2++) {
                bf16x8 vf = *(const bf16x8*)&Vc[(n2 * 16 + t) * 64 + (((ks2 * 64 + g * 16) ^ swzt) >> 1)];
                Oa[n2] = __builtin_amdgcn_mfma_f32_16x16x32_bf16(pa.v, vf, Oa[n2], 0, 0, 0);
            }
            __builtin_amdgcn_s_setprio(0);
        }

        if (more) {
            vmwait0();
            barrier_raw();
        }
    }

#pragma unroll
    for (int r = 0; r < 4; r++) {
        float lq = __shfl(l_r, (lane & 48) + g * 4 + r);
        float inv = 1.f / lq;
        int orow = q0 + w * 16 + g * 4 + r;
#pragma unroll
        for (int n2 = 0; n2 < 8; n2++)
            o[(size_t)(b * 1024 + orow) * 1024 + h * 128 + n2 * 16 + t] = f2bf(Oa[n2][r] * inv);
    }
}

extern "C" void kernel_launch(void* const* d_in, const int* in_sizes, int n_in,
                              void* d_out, int out_size, void* d_ws, size_t ws_size,
                              hipStream_t stream) {
    const float* x          = (const float*)d_in[0];
    const float* c          = (const float*)d_in[1];
    const float* m_ada_w    = (const float*)d_in[2];
    const float* m_ada_b    = (const float*)d_in[3];
    const float* m_norm_g   = (const float*)d_in[4];
    const float* m_norm_b   = (const float*)d_in[5];
    const float* in_proj_w  = (const float*)d_in[6];
    const float* in_proj_b  = (const float*)d_in[7];
    const float* out_proj_w = (const float*)d_in[8];
    const float* out_proj_b = (const float*)d_in[9];
    const float* f_ada_w    = (const float*)d_in[10];
    const float* f_ada_b    = (const float*)d_in[11];
    const float* f_norm_g   = (const float*)d_in[12];
    const float* f_norm_b   = (const float*)d_in[13];
    const float* w1         = (const float*)d_in[14];
    const float* b1         = (const float*)d_in[15];
    const float* w2         = (const float*)d_in[16];
    const float* b2         = (const float*)d_in[17];
    float* out = (float*)d_out;
    char* ws = (char*)d_ws;

    unsigned short* Wq   = (unsigned short*)(ws + 0);          // 3072x1024 bf16
    unsigned short* Wo   = (unsigned short*)(ws + 6291456);    // 1024x1024
    unsigned short* vt   = (unsigned short*)(ws + 8388608);    // 64x128x1024 (later W1t/W2t)
    unsigned short* W1t  = (unsigned short*)(ws + 8388608);    // 4096x1024
    unsigned short* W2t  = (unsigned short*)(ws + 16777216);   // 1024x4096
    float*          modm = (float*)(ws + 25165824);            // 8x3072
    float*          modf = (float*)(ws + 25264128);            // 8x3072
    unsigned short* hbuf = (unsigned short*)(ws + 25362432);   // 8192x1024
    float*          part = (float*)(ws + 25362432);            // ada partials (hbuf region)
    float*          part2= (float*)(ws + 25362432 + 2097152);
    unsigned short* qkv  = (unsigned short*)(ws + 42139648);   // 8192x3072
    unsigned short* obuf = (unsigned short*)(ws + 92471296);   // 8192x1024
    unsigned short* h2   = (unsigned short*)(ws + 42139648);   // 8192x4096 (aliases qkv+obuf)

    hipFuncSetAttribute((const void*)&gemm9<0>, hipFuncAttributeMaxDynamicSharedMemorySize, 65536);
    hipFuncSetAttribute((const void*)&gemm9<2>, hipFuncAttributeMaxDynamicSharedMemorySize, 65536);
    hipFuncSetAttribute((const void*)&gemmo<1>, hipFuncAttributeMaxDynamicSharedMemorySize, 32768);
    hipFuncSetAttribute((const void*)&gemmo<3>, hipFuncAttributeMaxDynamicSharedMemorySize, 32768);
    hipFuncSetAttribute((const void*)&attn_kernel, hipFuncAttributeMaxDynamicSharedMemorySize, 65536);

    hipLaunchKernelGGL(ada_mod_part, dim3(12, 16, 2), dim3(256), 0, stream,
                       c, m_ada_w, f_ada_w, part, part2);
    hipLaunchKernelGGL(ada_reduce, dim3(96, 2), dim3(256), 0, stream,
                       part, part2, m_ada_b, f_ada_b, modm, modf);

    hipLaunchKernelGGL(f2b4, dim3(3072), dim3(256), 0, stream, in_proj_w, Wq);
    hipLaunchKernelGGL(f2b4, dim3(1024), dim3(256), 0, stream, out_proj_w, Wo);

    hipLaunchKernelGGL(ln_mod_kernel, dim3(8192), dim3(256), 0, stream, x, m_norm_g, m_norm_b, modm, hbuf);
    // qkv: 32 row-panels x 12 cols = 384 blocks; V cols write vt directly
    hipLaunchKernelGGL(HIP_KERNEL_NAME(gemm9<0>), dim3(384), dim3(512), 65536, stream,
                       hbuf, Wq, 3072, 1024, 12, in_proj_b, qkv, vt);
    hipLaunchKernelGGL(attn_kernel, dim3(512), dim3(512), 65536, stream, qkv, vt, obuf);
    // out-proj: 64 x 8 = 512 blocks
    hipLaunchKernelGGL(HIP_KERNEL_NAME(gemmo<1>), dim3(512), dim3(256), 32768, stream,
                       obuf, Wo, 1024, 1024, 8, out_proj_b, x, modm, out);

    hipLaunchKernelGGL(transpose_f2b, dim3(128, 32), dim3(256), 0, stream, w1, W1t, 1024, 4096);
    hipLaunchKernelGGL(transpose_f2b, dim3(32, 128), dim3(256), 0, stream, w2, W2t, 4096, 1024);

    hipLaunchKernelGGL(ln_mod_kernel, dim3(8192), dim3(256), 0, stream, out, f_norm_g, f_norm_b, modf, hbuf);
    // FF1: 32 x 16 = 512 blocks
    hipLaunchKernelGGL(HIP_KERNEL_NAME(gemm9<2>), dim3(512), dim3(512), 65536, stream,
                       hbuf, W1t, 4096, 1024, 16, b1, h2, (unsigned short*)nullptr);
    // FF2: K=4096, 64 x 8 = 512 blocks
    hipLaunchKernelGGL(HIP_KERNEL_NAME(gemmo<3>), dim3(512), dim3(256), 32768, stream,
                       h2, W2t, 1024, 4096, 8, b2, (const float*)nullptr, modf, out);
}